// Round 1
// baseline (7688.637 us; speedup 1.0000x reference)
//
#include <hip/hip_runtime.h>
#include <math.h>

// Problem constants
#define DM    1024
#define FFD   4096
#define VOCAB 32000
#define NCAT  75
#define UNK_IDX 1
#define EPS   1e-5f
#define NB    8
#define SEQ   2048
#define T_TOK (NB*SEQ)   // 16384 tokens

// ---------------------------------------------------------------------------
// Embedding + sinusoidal positional encoding
// ---------------------------------------------------------------------------
__global__ __launch_bounds__(256)
void embed_pos_kernel(const int* __restrict__ idx,
                      const float* __restrict__ emb,
                      float* __restrict__ x)
{
    int gid = blockIdx.x * blockDim.x + threadIdx.x;   // over T_TOK*DM
    if (gid >= T_TOK * DM) return;
    int dcol = gid & (DM - 1);
    int tok  = gid >> 10;            // /DM
    int t    = tok & (SEQ - 1);      // position within sequence
    int id = idx[tok];
    if (id >= VOCAB || id < 0) id = UNK_IDX;
    int p = dcol >> 1;
    float power = (float)p / 512.0f;           // (2p)/DM
    float denom = powf(10000.0f, power);       // accurate powf (ang up to 2047)
    float ang = (float)t / denom;
    float pe = (dcol & 1) ? cosf(ang) : sinf(ang);
    x[gid] = emb[(long long)id * DM + dcol] + pe;
}

// ---------------------------------------------------------------------------
// Tiled fp32 GEMM: C = scale*(op(A) @ B) + bias, optional relu.
//   TRANS_A==0: A is [M,K] row-major; TRANS_A==1: A is [K,M] row-major.
// B is [K,N] row-major. Batched via blockIdx.z (element strides sA/sB/sC).
// BM=BN=64, BK=16, 256 threads, 4x4 micro-tile/thread. LDS rows padded to 68.
// ---------------------------------------------------------------------------
template<int TRANS_A>
__global__ __launch_bounds__(256)
void gemm_f32(const float* __restrict__ A, const float* __restrict__ B,
              const float* __restrict__ bias, float* __restrict__ C,
              int M, int N, int K,
              long long sA, long long sB, long long sC,
              float scale, int do_relu)
{
    A += (long long)blockIdx.z * sA;
    B += (long long)blockIdx.z * sB;
    C += (long long)blockIdx.z * sC;
    const int tid  = threadIdx.x;
    const int row0 = blockIdx.y * 64;
    const int col0 = blockIdx.x * 64;

    __shared__ float As[16][68];
    __shared__ float Bs[16][68];

    float acc[4][4];
#pragma unroll
    for (int i = 0; i < 4; i++)
#pragma unroll
        for (int j = 0; j < 4; j++) acc[i][j] = 0.f;

    const int ty = tid >> 4;   // output rows ty*4..+3
    const int tx = tid & 15;   // output cols tx*4..+3

    for (int k0 = 0; k0 < K; k0 += 16) {
        if (TRANS_A) {
            int m  = tid & 63;
            int kk = tid >> 6;
#pragma unroll
            for (int p = 0; p < 4; p++) {
                int k  = kk * 4 + p;
                int gm = row0 + m;
                As[k][m] = (gm < M) ? A[(long long)(k0 + k) * M + gm] : 0.f;
            }
        } else {
            int kc = tid & 15;
            int r4 = tid >> 4;
#pragma unroll
            for (int p = 0; p < 4; p++) {
                int r  = r4 + p * 16;
                int gr = row0 + r;
                As[kc][r] = (gr < M) ? A[(long long)gr * K + (k0 + kc)] : 0.f;
            }
        }
        {
            int n  = tid & 63;
            int kk = tid >> 6;
#pragma unroll
            for (int p = 0; p < 4; p++) {
                int k  = kk * 4 + p;
                int gn = col0 + n;
                Bs[k][n] = (gn < N) ? B[(long long)(k0 + k) * N + gn] : 0.f;
            }
        }
        __syncthreads();
#pragma unroll
        for (int kk = 0; kk < 16; ++kk) {
            float a[4], b[4];
#pragma unroll
            for (int i = 0; i < 4; i++) a[i] = As[kk][ty * 4 + i];
#pragma unroll
            for (int j = 0; j < 4; j++) b[j] = Bs[kk][tx * 4 + j];
#pragma unroll
            for (int i = 0; i < 4; i++)
#pragma unroll
                for (int j = 0; j < 4; j++)
                    acc[i][j] = fmaf(a[i], b[j], acc[i][j]);
        }
        __syncthreads();
    }

#pragma unroll
    for (int i = 0; i < 4; i++) {
        int gr = row0 + ty * 4 + i;
        if (gr >= M) continue;
#pragma unroll
        for (int j = 0; j < 4; j++) {
            int gc = col0 + tx * 4 + j;
            if (gc >= N) continue;
            float v = acc[i][j] * scale;
            if (bias) v += bias[gc];
            if (do_relu) v = fmaxf(v, 0.f);
            C[(long long)gr * N + gc] = v;
        }
    }
}

// ---------------------------------------------------------------------------
// out[row,:] = LN(X[row,:] + Y[row,:]) * g + b   over DM=1024, one block/row
// ---------------------------------------------------------------------------
__global__ __launch_bounds__(256)
void add_ln_kernel(const float* __restrict__ X, const float* __restrict__ Y,
                   const float* __restrict__ g, const float* __restrict__ b,
                   float* __restrict__ out)
{
    int row = blockIdx.x;
    int tid = threadIdx.x;
    const float* xr = X + (long long)row * DM;
    const float* yr = Y + (long long)row * DM;
    float v[4];
    float s = 0.f, s2 = 0.f;
#pragma unroll
    for (int i = 0; i < 4; i++) {
        int c = tid + i * 256;
        v[i] = xr[c] + yr[c];
        s  += v[i];
        s2 += v[i] * v[i];
    }
#pragma unroll
    for (int o = 1; o < 64; o <<= 1) {
        s  += __shfl_xor(s,  o, 64);
        s2 += __shfl_xor(s2, o, 64);
    }
    __shared__ float rs[4], rs2[4], stats[2];
    int wid = tid >> 6;
    if ((tid & 63) == 0) { rs[wid] = s; rs2[wid] = s2; }
    __syncthreads();
    if (tid == 0) {
        float S  = rs[0] + rs[1] + rs[2] + rs[3];
        float S2 = rs2[0] + rs2[1] + rs2[2] + rs2[3];
        float mean = S / (float)DM;
        float var  = S2 / (float)DM - mean * mean;   // biased var == jnp.var
        stats[0] = mean;
        stats[1] = rsqrtf(var + EPS);
    }
    __syncthreads();
    float mean = stats[0], rstd = stats[1];
#pragma unroll
    for (int i = 0; i < 4; i++) {
        int c = tid + i * 256;
        out[(long long)row * DM + c] = (v[i] - mean) * rstd * g[c] + b[c];
    }
}

// ---------------------------------------------------------------------------
// out[row,:] = sigmoid(LN75(L[row,:]) * g + b), one 64-lane wave per row
// ---------------------------------------------------------------------------
__global__ __launch_bounds__(64)
void ln75_sigmoid_kernel(const float* __restrict__ L,
                         const float* __restrict__ g, const float* __restrict__ b,
                         float* __restrict__ out)
{
    int row = blockIdx.x;
    int t   = threadIdx.x;
    const float* lr = L + (long long)row * NCAT;
    float e0 = (t < NCAT) ? lr[t] : 0.f;
    float e1 = (t + 64 < NCAT) ? lr[t + 64] : 0.f;
    float s  = e0 + e1;
    float s2 = e0 * e0 + e1 * e1;
#pragma unroll
    for (int o = 1; o < 64; o <<= 1) {
        s  += __shfl_xor(s,  o, 64);
        s2 += __shfl_xor(s2, o, 64);
    }
    float mean = s / (float)NCAT;
    float var  = s2 / (float)NCAT - mean * mean;
    float rstd = rsqrtf(var + EPS);
    if (t < NCAT) {
        float z = (e0 - mean) * rstd * g[t] + b[t];
        out[(long long)row * NCAT + t] = 1.f / (1.f + expf(-z));
    }
    if (t + 64 < NCAT) {
        float z = (e1 - mean) * rstd * g[t + 64] + b[t + 64];
        out[(long long)row * NCAT + t + 64] = 1.f / (1.f + expf(-z));
    }
}

// ---------------------------------------------------------------------------
// Attention reassociated: (QK^T/8)V == Q @ (K^T V * 0.125) — no n x n scores.
// Workspace (floats), total ~93.5M = 374 MB:
//   X[16384,1024] (x -> ffo), Q[.. ] (q -> h1), Kb (k -> attn -> h2),
//   Vb (v -> u -> l1), KTV[8,1024,1024], F1[4096,4096], LOG[16384,75]
// ---------------------------------------------------------------------------
extern "C" void kernel_launch(void* const* d_in, const int* in_sizes, int n_in,
                              void* d_out, int out_size, void* d_ws, size_t ws_size,
                              hipStream_t stream)
{
    const int*   idx = (const int*)  d_in[0];
    const float* emb = (const float*)d_in[1];
    const float* Wq  = (const float*)d_in[2];
    const float* bq  = (const float*)d_in[3];
    const float* Wk  = (const float*)d_in[4];
    const float* bk  = (const float*)d_in[5];
    const float* Wv  = (const float*)d_in[6];
    const float* bv  = (const float*)d_in[7];
    const float* Wu  = (const float*)d_in[8];
    const float* bu  = (const float*)d_in[9];
    const float* g1  = (const float*)d_in[10];
    const float* be1 = (const float*)d_in[11];
    const float* W1  = (const float*)d_in[12];
    const float* b1  = (const float*)d_in[13];
    const float* W2  = (const float*)d_in[14];
    const float* b2  = (const float*)d_in[15];
    const float* g2  = (const float*)d_in[16];
    const float* be2 = (const float*)d_in[17];
    const float* W3  = (const float*)d_in[18];
    const float* b3  = (const float*)d_in[19];
    const float* W4  = (const float*)d_in[20];
    const float* b4  = (const float*)d_in[21];
    const float* g3  = (const float*)d_in[22];
    const float* be3 = (const float*)d_in[23];

    float* ws = (float*)d_ws;
    const long long TK = (long long)T_TOK;
    float* X   = ws;
    float* Q   = X   + TK * DM;
    float* Kb  = Q   + TK * DM;
    float* Vb  = Kb  + TK * DM;
    float* KTV = Vb  + TK * DM;
    float* F1  = KTV + (long long)NB * DM * DM;
    float* LOG = F1  + (long long)4096 * FFD;
    float* out = (float*)d_out;

    dim3 blk(256);

    // x = emb[idx] + pos
    embed_pos_kernel<<<(T_TOK * DM + 255) / 256, 256, 0, stream>>>(idx, emb, X);

    // q, k, v
    gemm_f32<0><<<dim3(16, 256, 1), blk, 0, stream>>>(X, Wq, bq, Q,  T_TOK, DM, DM, 0, 0, 0, 1.f, 0);
    gemm_f32<0><<<dim3(16, 256, 1), blk, 0, stream>>>(X, Wk, bk, Kb, T_TOK, DM, DM, 0, 0, 0, 1.f, 0);
    gemm_f32<0><<<dim3(16, 256, 1), blk, 0, stream>>>(X, Wv, bv, Vb, T_TOK, DM, DM, 0, 0, 0, 1.f, 0);

    // ktv[b] = (K[b]^T @ V[b]) * 0.125
    gemm_f32<1><<<dim3(16, 16, NB), blk, 0, stream>>>(Kb, Vb, nullptr, KTV,
        DM, DM, SEQ, (long long)SEQ * DM, (long long)SEQ * DM, (long long)DM * DM, 0.125f, 0);

    // attn[b] = Q[b] @ ktv[b] -> Kb
    gemm_f32<0><<<dim3(16, 32, NB), blk, 0, stream>>>(Q, KTV, nullptr, Kb,
        SEQ, DM, DM, (long long)SEQ * DM, (long long)DM * DM, (long long)SEQ * DM, 1.f, 0);

    // u = attn @ Wu + bu -> Vb
    gemm_f32<0><<<dim3(16, 256, 1), blk, 0, stream>>>(Kb, Wu, bu, Vb, T_TOK, DM, DM, 0, 0, 0, 1.f, 0);

    // h1 = LN(x + u) -> Q
    add_ln_kernel<<<T_TOK, 256, 0, stream>>>(X, Vb, g1, be1, Q);

    // FFN chunked over M by 4096: ff1 = relu(h1@W1+b1) -> F1; ffo = ff1@W2+b2 -> X
    for (int c = 0; c < 4; c++) {
        const float* h1c  = Q + (long long)c * 4096 * DM;
        float*       ffoc = X + (long long)c * 4096 * DM;
        gemm_f32<0><<<dim3(64, 64, 1), blk, 0, stream>>>(h1c, W1, b1, F1,  4096, FFD, DM, 0, 0, 0, 1.f, 1);
        gemm_f32<0><<<dim3(16, 64, 1), blk, 0, stream>>>(F1, W2, b2, ffoc, 4096, DM, FFD, 0, 0, 0, 1.f, 0);
    }

    // h2 = LN(h1 + ffo) -> Kb
    add_ln_kernel<<<T_TOK, 256, 0, stream>>>(Q, X, g2, be2, Kb);

    // l1 = relu(h2 @ W3 + b3) -> Vb   [16384,512]
    gemm_f32<0><<<dim3(8, 256, 1), blk, 0, stream>>>(Kb, W3, b3, Vb, T_TOK, 512, DM, 0, 0, 0, 1.f, 1);

    // logits = l1 @ W4 + b4 -> LOG   [16384,75]
    gemm_f32<0><<<dim3(2, 256, 1), blk, 0, stream>>>(Vb, W4, b4, LOG, T_TOK, NCAT, 512, 0, 0, 0, 1.f, 0);

    // out = sigmoid(LN75(logits))
    ln75_sigmoid_kernel<<<T_TOK, 64, 0, stream>>>(LOG, g3, be3, out);
}

// Round 3
// 2542.561 us; speedup vs baseline: 3.0240x; 3.0240x over previous
//
#include <hip/hip_runtime.h>
#include <hip/hip_bf16.h>
#include <math.h>

// Problem constants
#define DM    1024
#define FFD   4096
#define VOCAB 32000
#define NCAT  75
#define UNK_IDX 1
#define EPS   1e-5f
#define NB    8
#define SEQ   2048
#define T_TOK (NB*SEQ)   // 16384 tokens

using u16    = unsigned short;
using short8 = __attribute__((ext_vector_type(8))) short;   // 8 bf16 = 4 VGPRs
using f32x4  = __attribute__((ext_vector_type(4))) float;   // MFMA C/D frag

struct alignas(8) us4 { u16 s[4]; };

// round-to-nearest-even fp32 -> bf16 bits
__device__ __forceinline__ u16 bf_rne(float f) {
    unsigned u = __float_as_uint(f);
    return (u16)((u + 0x7FFF + ((u >> 16) & 1)) >> 16);
}
__device__ __forceinline__ float bf_val(u16 h) {
    return __uint_as_float((unsigned)h << 16);
}
// split f into hi + lo bf16 (hi+lo ~= f to ~2^-17 rel)
__device__ __forceinline__ void bf_split(float f, u16& hi, u16& lo) {
    hi = bf_rne(f);
    lo = bf_rne(f - bf_val(hi));
}

// async global->LDS, 16 B per lane; LDS dest = wave-uniform base + lane*16
__device__ __forceinline__ void async16(const u16* g, u16* l) {
    __builtin_amdgcn_global_load_lds(
        (const __attribute__((address_space(1))) void*)g,
        (__attribute__((address_space(3))) void*)l,
        16, 0, 0);
}

// ---------------------------------------------------------------------------
// Embedding + sinusoidal positional encoding -> Xf (fp32) and XH/XL (split)
// ---------------------------------------------------------------------------
__global__ __launch_bounds__(256)
void embed_pos_kernel(const int* __restrict__ idx,
                      const float* __restrict__ emb,
                      float* __restrict__ xf,
                      u16* __restrict__ xh, u16* __restrict__ xl)
{
    int gid = blockIdx.x * blockDim.x + threadIdx.x;   // over T_TOK*DM
    if (gid >= T_TOK * DM) return;
    int dcol = gid & (DM - 1);
    int tok  = gid >> 10;
    int t    = tok & (SEQ - 1);
    int id = idx[tok];
    if (id >= VOCAB || id < 0) id = UNK_IDX;
    int p = dcol >> 1;
    float power = (float)p / 512.0f;
    float denom = powf(10000.0f, power);
    float ang = (float)t / denom;
    float pe = (dcol & 1) ? cosf(ang) : sinf(ang);
    float v = emb[(long long)id * DM + dcol] + pe;
    xf[gid] = v;
    u16 h, l; bf_split(v, h, l);
    xh[gid] = h; xl[gid] = l;
}

// ---------------------------------------------------------------------------
// Weight transpose + split: in [K,N] fp32 -> outH/outL [Npad,K] bf16 bits
// rows n in [N,Npad) zero-filled (pads W4 75 -> 128).
// ---------------------------------------------------------------------------
__global__ __launch_bounds__(256)
void transpose_split_kernel(const float* __restrict__ in,
                            u16* __restrict__ outH, u16* __restrict__ outL,
                            int K, int N, int Npad)
{
    __shared__ float t[32][33];
    int n0 = blockIdx.x * 32, k0 = blockIdx.y * 32;
    int tx = threadIdx.x & 31, ty = threadIdx.x >> 5;   // ty 0..7
#pragma unroll
    for (int i = 0; i < 4; i++) {
        int k = k0 + ty + i * 8, n = n0 + tx;
        t[ty + i * 8][tx] = (k < K && n < N) ? in[(long long)k * N + n] : 0.f;
    }
    __syncthreads();
#pragma unroll
    for (int i = 0; i < 4; i++) {
        int n = n0 + ty + i * 8, k = k0 + tx;
        if (n < Npad && k < K) {
            u16 h, l; bf_split(t[tx][ty + i * 8], h, l);
            outH[(long long)n * K + k] = h;
            outL[(long long)n * K + k] = l;
        }
    }
}

// pad b4 [75] -> b4p [128]
__global__ __launch_bounds__(128)
void pad_bias_kernel(const float* __restrict__ b, float* __restrict__ bp)
{
    int i = threadIdx.x;
    bp[i] = (i < NCAT) ? b[i] : 0.f;
}

// ---------------------------------------------------------------------------
// Split-bf16 MFMA NT GEMM (emulated fp32): C = scale*(A @ B^T) + bias [,relu]
//   A = Ahi+Alo [M,K], B = Bhi+Blo [N,K], K-contiguous. fp32 accumulate.
//   3 MFMA passes: a_lo*b_hi + a_hi*b_lo + a_hi*b_hi  (lo*lo negligible).
//   128x128 tile, BK=32, 256 thr = 4 waves (2x2), 4x4 16x16x32 MFMA per wave.
//   Requires M%128==0, N%128==0, K%32==0.
// OUT_MODE: 0 = fp32 [M,N] to Chi; 1 = split bf16 pair [M,N];
//           2 = split bf16 KV-transposed [b][n][t], b=row>>11, t=row&2047.
// ---------------------------------------------------------------------------
template<int OUT_MODE>
__global__ __launch_bounds__(256)
void gemm3_nt(const u16* __restrict__ Ahi, const u16* __restrict__ Alo,
              const u16* __restrict__ Bhi, const u16* __restrict__ Blo,
              const float* __restrict__ bias,
              void* __restrict__ Chi, void* __restrict__ Clo,
              int M, int N, int K,
              long long sA, long long sB, long long sC,
              float scale, int do_relu)
{
    Ahi += (long long)blockIdx.z * sA;  Alo += (long long)blockIdx.z * sA;
    Bhi += (long long)blockIdx.z * sB;  Blo += (long long)blockIdx.z * sB;
    const int tid  = threadIdx.x;
    const int lane = tid & 63;
    const int w    = tid >> 6;          // wave 0..3
    const int wm   = w >> 1, wn = w & 1;
    const long long row0 = (long long)blockIdx.y * 128;
    const long long col0 = (long long)blockIdx.x * 128;

    __shared__ u16 AsH[128 * 32];
    __shared__ u16 AsL[128 * 32];
    __shared__ u16 BsH[128 * 32];
    __shared__ u16 BsL[128 * 32];

    f32x4 acc[4][4];
    const f32x4 zero = {0.f, 0.f, 0.f, 0.f};
#pragma unroll
    for (int i = 0; i < 4; i++)
#pragma unroll
        for (int j = 0; j < 4; j++) acc[i][j] = zero;

    const int ldrow = lane >> 2;          // row within 16-row chunk
    const int lcol8 = (lane & 3) * 8;     // this lane's 16 B (8 elems)
    const int fr    = lane & 15;          // fragment row (m or n)
    const int kk8   = (lane >> 4) * 8;    // fragment k offset

    for (int k0 = 0; k0 < K; k0 += 32) {
        __syncthreads();
#pragma unroll
        for (int it = 0; it < 2; ++it) {
            int rb = (it * 4 + w) * 16;   // wave-uniform 16-row chunk
            long long ao = (row0 + rb + ldrow) * (long long)K + k0 + lcol8;
            long long bo = (col0 + rb + ldrow) * (long long)K + k0 + lcol8;
            async16(Ahi + ao, AsH + rb * 32);
            async16(Alo + ao, AsL + rb * 32);
            async16(Bhi + bo, BsH + rb * 32);
            async16(Blo + bo, BsL + rb * 32);
        }
        __syncthreads();

        short8 ah[4], al[4], bh[4], bl[4];
#pragma unroll
        for (int i = 0; i < 4; ++i) {
            int off = (wm * 64 + i * 16 + fr) * 32 + kk8;
            ah[i] = *(const short8*)(AsH + off);
            al[i] = *(const short8*)(AsL + off);
        }
#pragma unroll
        for (int j = 0; j < 4; ++j) {
            int off = (wn * 64 + j * 16 + fr) * 32 + kk8;
            bh[j] = *(const short8*)(BsH + off);
            bl[j] = *(const short8*)(BsL + off);
        }
#pragma unroll
        for (int i = 0; i < 4; ++i)
#pragma unroll
            for (int j = 0; j < 4; ++j) {
                acc[i][j] = __builtin_amdgcn_mfma_f32_16x16x32_bf16(al[i], bh[j], acc[i][j], 0, 0, 0);
                acc[i][j] = __builtin_amdgcn_mfma_f32_16x16x32_bf16(ah[i], bl[j], acc[i][j], 0, 0, 0);
                acc[i][j] = __builtin_amdgcn_mfma_f32_16x16x32_bf16(ah[i], bh[j], acc[i][j], 0, 0, 0);
            }
    }

    // Epilogue. C/D layout: col = lane&15, row = (lane>>4)*4 + reg
    const int qr = (lane >> 4) * 4;
    const int lc = lane & 15;
#pragma unroll
    for (int i = 0; i < 4; ++i) {
#pragma unroll
        for (int j = 0; j < 4; ++j) {
            long long gc = col0 + wn * 64 + j * 16 + lc;
            float bv = bias ? bias[gc] : 0.f;
            if (OUT_MODE == 2) {
                long long gr = row0 + wm * 64 + i * 16 + qr;  // 4 consecutive tokens
                int b  = (int)(gr >> 11);
                int tl = (int)(gr & (SEQ - 1));
                us4 ph, pl;
#pragma unroll
                for (int r = 0; r < 4; ++r) {
                    float f = acc[i][j][r] * scale + bv;
                    if (do_relu) f = fmaxf(f, 0.f);
                    u16 h, l; bf_split(f, h, l);
                    ph.s[r] = h; pl.s[r] = l;
                }
                long long base = (long long)b * N * SEQ + gc * SEQ + tl;
                *(us4*)((u16*)Chi + base) = ph;
                *(us4*)((u16*)Clo + base) = pl;
            } else if (OUT_MODE == 1) {
                u16* CH = (u16*)Chi + blockIdx.z * sC;
                u16* CL = (u16*)Clo + blockIdx.z * sC;
#pragma unroll
                for (int r = 0; r < 4; ++r) {
                    long long gr = row0 + wm * 64 + i * 16 + qr + r;
                    float f = acc[i][j][r] * scale + bv;
                    if (do_relu) f = fmaxf(f, 0.f);
                    u16 h, l; bf_split(f, h, l);
                    CH[gr * N + gc] = h;
                    CL[gr * N + gc] = l;
                }
            } else {
                float* C = (float*)Chi + blockIdx.z * sC;
#pragma unroll
                for (int r = 0; r < 4; ++r) {
                    long long gr = row0 + wm * 64 + i * 16 + qr + r;
                    float f = acc[i][j][r] * scale + bv;
                    if (do_relu) f = fmaxf(f, 0.f);
                    C[gr * N + gc] = f;
                }
            }
        }
    }
}

// ---------------------------------------------------------------------------
// LN(X + Y) * g + b over DM=1024; writes fp32 (nullable) and split pair
// ---------------------------------------------------------------------------
__global__ __launch_bounds__(256)
void add_ln_kernel(const float* __restrict__ X, const float* __restrict__ Y,
                   const float* __restrict__ g, const float* __restrict__ b,
                   float* __restrict__ outf,
                   u16* __restrict__ outh, u16* __restrict__ outl)
{
    int row = blockIdx.x;
    int tid = threadIdx.x;
    const float* xr = X + (long long)row * DM;
    const float* yr = Y + (long long)row * DM;
    float v[4];
    float s = 0.f, s2 = 0.f;
#pragma unroll
    for (int i = 0; i < 4; i++) {
        int c = tid + i * 256;
        v[i] = xr[c] + yr[c];
        s  += v[i];
        s2 += v[i] * v[i];
    }
#pragma unroll
    for (int o = 1; o < 64; o <<= 1) {
        s  += __shfl_xor(s,  o, 64);
        s2 += __shfl_xor(s2, o, 64);
    }
    __shared__ float rs[4], rs2[4], stats[2];
    int wid = tid >> 6;
    if ((tid & 63) == 0) { rs[wid] = s; rs2[wid] = s2; }
    __syncthreads();
    if (tid == 0) {
        float S  = rs[0] + rs[1] + rs[2] + rs[3];
        float S2 = rs2[0] + rs2[1] + rs2[2] + rs2[3];
        float mean = S / (float)DM;
        float var  = S2 / (float)DM - mean * mean;   // biased var == jnp.var
        stats[0] = mean;
        stats[1] = rsqrtf(var + EPS);
    }
    __syncthreads();
    float mean = stats[0], rstd = stats[1];
#pragma unroll
    for (int i = 0; i < 4; i++) {
        int c = tid + i * 256;
        float o = (v[i] - mean) * rstd * g[c] + b[c];
        if (outf) outf[(long long)row * DM + c] = o;
        u16 h, l; bf_split(o, h, l);
        outh[(long long)row * DM + c] = h;
        outl[(long long)row * DM + c] = l;
    }
}

// ---------------------------------------------------------------------------
// out[row,:] = sigmoid(LN75(L[row,0:75]) * g + b); L leading dim 128
// ---------------------------------------------------------------------------
__global__ __launch_bounds__(64)
void ln75_sigmoid_kernel(const float* __restrict__ L,
                         const float* __restrict__ g, const float* __restrict__ b,
                         float* __restrict__ out)
{
    int row = blockIdx.x;
    int t   = threadIdx.x;
    const float* lr = L + (long long)row * 128;
    float e0 = (t < NCAT) ? lr[t] : 0.f;
    float e1 = (t + 64 < NCAT) ? lr[t + 64] : 0.f;
    float s  = e0 + e1;
    float s2 = e0 * e0 + e1 * e1;
#pragma unroll
    for (int o = 1; o < 64; o <<= 1) {
        s  += __shfl_xor(s,  o, 64);
        s2 += __shfl_xor(s2, o, 64);
    }
    float mean = s / (float)NCAT;
    float var  = s2 / (float)NCAT - mean * mean;
    float rstd = rsqrtf(var + EPS);
    if (t < NCAT) {
        float z = (e0 - mean) * rstd * g[t] + b[t];
        out[(long long)row * NCAT + t] = 1.f / (1.f + expf(-z));
    }
    if (t + 64 < NCAT) {
        float z = (e1 - mean) * rstd * g[t + 64] + b[t + 64];
        out[(long long)row * NCAT + t + 64] = 1.f / (1.f + expf(-z));
    }
}

// ---------------------------------------------------------------------------
// Orchestration. Attention reassociated: (QK^T/8)V == Q @ (K^T V * 0.125).
// All tensors flowing into GEMMs are split hi/lo bf16 pairs (emulated fp32).
// Region reuse plan (lifetimes verified, ~410 MB):
//   R_A 64MB: Xf fp32      -> ffo fp32
//   R_B 64MB: X hi|lo      -> attn hi|lo -> h2 hi|lo
//   R_C 64MB: Q hi|lo      -> h1 hi|lo
//   R_D 64MB: Kt hi|lo     -> u fp32     -> ff1 chunk hi|lo (4096x4096)
//   R_E 64MB: Vt hi|lo     -> h1f fp32
//   R_F 32MB: KTVt hi|lo   -> l1 hi|lo
//   R_G  8MB: LOG fp32 [16384,128]
// ---------------------------------------------------------------------------
extern "C" void kernel_launch(void* const* d_in, const int* in_sizes, int n_in,
                              void* d_out, int out_size, void* d_ws, size_t ws_size,
                              hipStream_t stream)
{
    const int*   idx = (const int*)  d_in[0];
    const float* emb = (const float*)d_in[1];
    const float* Wq  = (const float*)d_in[2];
    const float* bq  = (const float*)d_in[3];
    const float* Wk  = (const float*)d_in[4];
    const float* bk  = (const float*)d_in[5];
    const float* Wv  = (const float*)d_in[6];
    const float* bv  = (const float*)d_in[7];
    const float* Wu  = (const float*)d_in[8];
    const float* bu  = (const float*)d_in[9];
    const float* g1  = (const float*)d_in[10];
    const float* be1 = (const float*)d_in[11];
    const float* W1  = (const float*)d_in[12];
    const float* b1  = (const float*)d_in[13];
    const float* W2  = (const float*)d_in[14];
    const float* b2  = (const float*)d_in[15];
    const float* g2  = (const float*)d_in[16];
    const float* be2 = (const float*)d_in[17];
    const float* W3  = (const float*)d_in[18];
    const float* b3  = (const float*)d_in[19];
    const float* W4  = (const float*)d_in[20];
    const float* b4  = (const float*)d_in[21];
    const float* g3  = (const float*)d_in[22];
    const float* be3 = (const float*)d_in[23];

    const long long TD  = (long long)T_TOK * DM;       // 16.78M
    char* p = (char*)d_ws;
    char* R_A = p; p += TD * 4;
    char* R_B = p; p += TD * 4;
    char* R_C = p; p += TD * 4;
    char* R_D = p; p += TD * 4;
    char* R_E = p; p += TD * 4;
    char* R_F = p; p += (long long)NB * DM * DM * 4;   // 32 MB
    char* R_G = p; p += (long long)T_TOK * 128 * 4;    // 8 MB
    u16* WqH = (u16*)p; p += DM*DM*2;     u16* WqL = (u16*)p; p += DM*DM*2;
    u16* WkH = (u16*)p; p += DM*DM*2;     u16* WkL = (u16*)p; p += DM*DM*2;
    u16* WvH = (u16*)p; p += DM*DM*2;     u16* WvL = (u16*)p; p += DM*DM*2;
    u16* WuH = (u16*)p; p += DM*DM*2;     u16* WuL = (u16*)p; p += DM*DM*2;
    u16* W1H = (u16*)p; p += (long long)FFD*DM*2;  u16* W1L = (u16*)p; p += (long long)FFD*DM*2;
    u16* W2H = (u16*)p; p += (long long)DM*FFD*2;  u16* W2L = (u16*)p; p += (long long)DM*FFD*2;
    u16* W3H = (u16*)p; p += 512*DM*2;    u16* W3L = (u16*)p; p += 512*DM*2;
    u16* W4H = (u16*)p; p += 128*512*2;   u16* W4L = (u16*)p; p += 128*512*2;
    float* b4p = (float*)p; p += 128*4;

    float* Xf   = (float*)R_A;
    float* ffo  = (float*)R_A;
    u16*   XH   = (u16*)R_B;              u16* XL   = XH + TD;
    u16*   attnH= (u16*)R_B;              u16* attnL= attnH + TD;
    u16*   h2H  = (u16*)R_B;              u16* h2L  = h2H + TD;
    u16*   QH   = (u16*)R_C;              u16* QL   = QH + TD;
    u16*   h1H  = (u16*)R_C;              u16* h1L  = h1H + TD;
    u16*   KtH  = (u16*)R_D;              u16* KtL  = KtH + TD;
    float* u    = (float*)R_D;
    u16*   f1H  = (u16*)R_D;              u16* f1L  = f1H + (long long)4096*FFD;
    u16*   VtH  = (u16*)R_E;              u16* VtL  = VtH + TD;
    float* h1f  = (float*)R_E;
    u16*   ktvH = (u16*)R_F;              u16* ktvL = ktvH + (long long)NB*DM*DM;
    u16*   l1H  = (u16*)R_F;              u16* l1L  = l1H + (long long)T_TOK*512;
    float* LOG  = (float*)R_G;
    float* out  = (float*)d_out;

    dim3 blk(256);

    // ---- weight transpose + split ---------------------------------------
    transpose_split_kernel<<<dim3(32, 32),  blk, 0, stream>>>(Wq, WqH, WqL, DM, DM, DM);
    transpose_split_kernel<<<dim3(32, 32),  blk, 0, stream>>>(Wk, WkH, WkL, DM, DM, DM);
    transpose_split_kernel<<<dim3(32, 32),  blk, 0, stream>>>(Wv, WvH, WvL, DM, DM, DM);
    transpose_split_kernel<<<dim3(32, 32),  blk, 0, stream>>>(Wu, WuH, WuL, DM, DM, DM);
    transpose_split_kernel<<<dim3(128, 32), blk, 0, stream>>>(W1, W1H, W1L, DM, FFD, FFD);
    transpose_split_kernel<<<dim3(32, 128), blk, 0, stream>>>(W2, W2H, W2L, FFD, DM, DM);
    transpose_split_kernel<<<dim3(16, 32),  blk, 0, stream>>>(W3, W3H, W3L, DM, 512, 512);
    transpose_split_kernel<<<dim3(4, 16),   blk, 0, stream>>>(W4, W4H, W4L, 512, NCAT, 128);
    pad_bias_kernel<<<1, 128, 0, stream>>>(b4, b4p);

    // ---- x = emb[idx] + pos ---------------------------------------------
    embed_pos_kernel<<<(T_TOK * DM + 255) / 256, blk, 0, stream>>>(idx, emb, Xf, XH, XL);

    // ---- QKV: Q normal; K,V transposed [b][dm][seq] ---------------------
    gemm3_nt<1><<<dim3(8, 128, 1), blk, 0, stream>>>(XH, XL, WqH, WqL, bq, QH, QL,
        T_TOK, DM, DM, 0, 0, 0, 1.f, 0);
    gemm3_nt<2><<<dim3(8, 128, 1), blk, 0, stream>>>(XH, XL, WkH, WkL, bk, KtH, KtL,
        T_TOK, DM, DM, 0, 0, 0, 1.f, 0);
    gemm3_nt<2><<<dim3(8, 128, 1), blk, 0, stream>>>(XH, XL, WvH, WvL, bv, VtH, VtL,
        T_TOK, DM, DM, 0, 0, 0, 1.f, 0);

    // ---- KTV^T[b] = NT(Vt[b], Kt[b]) * 0.125   [8][1024][1024] ----------
    gemm3_nt<1><<<dim3(8, 8, NB), blk, 0, stream>>>(VtH, VtL, KtH, KtL, nullptr, ktvH, ktvL,
        DM, DM, SEQ, (long long)DM * SEQ, (long long)DM * SEQ, (long long)DM * DM, 0.125f, 0);

    // ---- attn[b] = NT(Q[b], KTV^T[b])   [8][2048][1024] -----------------
    gemm3_nt<1><<<dim3(8, 16, NB), blk, 0, stream>>>(QH, QL, ktvH, ktvL, nullptr, attnH, attnL,
        SEQ, DM, DM, (long long)SEQ * DM, (long long)DM * DM, (long long)SEQ * DM, 1.f, 0);

    // ---- u = attn @ Wu + bu  (fp32) -------------------------------------
    gemm3_nt<0><<<dim3(8, 128, 1), blk, 0, stream>>>(attnH, attnL, WuH, WuL, bu, u, nullptr,
        T_TOK, DM, DM, 0, 0, 0, 1.f, 0);

    // ---- h1 = LN(x + u): fp32 + split -----------------------------------
    add_ln_kernel<<<T_TOK, blk, 0, stream>>>(Xf, u, g1, be1, h1f, h1H, h1L);

    // ---- FFN chunked over M by 4096 (ff1 chunk lives in R_D) ------------
    for (int c = 0; c < 4; c++) {
        const u16* h1Hc = h1H + (long long)c * 4096 * DM;
        const u16* h1Lc = h1L + (long long)c * 4096 * DM;
        float*     ffoc = ffo + (long long)c * 4096 * DM;
        gemm3_nt<1><<<dim3(32, 32, 1), blk, 0, stream>>>(h1Hc, h1Lc, W1H, W1L, b1, f1H, f1L,
            4096, FFD, DM, 0, 0, 0, 1.f, 1);
        gemm3_nt<0><<<dim3(8, 32, 1), blk, 0, stream>>>(f1H, f1L, W2H, W2L, b2, ffoc, nullptr,
            4096, DM, FFD, 0, 0, 0, 1.f, 0);
    }

    // ---- h2 = LN(h1 + ffo): split only ----------------------------------
    add_ln_kernel<<<T_TOK, blk, 0, stream>>>(h1f, ffo, g2, be2, nullptr, h2H, h2L);

    // ---- head: l1 = relu(h2@W3+b3) split; LOG = l1@W4p + b4p (N=128) ----
    gemm3_nt<1><<<dim3(4, 128, 1), blk, 0, stream>>>(h2H, h2L, W3H, W3L, b3, l1H, l1L,
        T_TOK, 512, DM, 0, 0, 0, 1.f, 1);
    gemm3_nt<0><<<dim3(1, 128, 1), blk, 0, stream>>>(l1H, l1L, W4H, W4L, b4p, LOG, nullptr,
        T_TOK, 128, 512, 0, 0, 0, 1.f, 0);

    // ---- out = sigmoid(LN75(logits)) ------------------------------------
    ln75_sigmoid_kernel<<<T_TOK, 64, 0, stream>>>(LOG, g3, be3, out);
}

// Round 4
// 2160.539 us; speedup vs baseline: 3.5587x; 1.1768x over previous
//
#include <hip/hip_runtime.h>
#include <hip/hip_bf16.h>
#include <math.h>

// Problem constants
#define DM    1024
#define FFD   4096
#define VOCAB 32000
#define NCAT  75
#define UNK_IDX 1
#define EPS   1e-5f
#define NB    8
#define SEQ   2048
#define T_TOK (NB*SEQ)   // 16384 tokens

using u16    = unsigned short;
using short8 = __attribute__((ext_vector_type(8))) short;   // 8 bf16 = 4 VGPRs
using f32x4  = __attribute__((ext_vector_type(4))) float;   // MFMA C/D frag

struct alignas(8) us4 { u16 s[4]; };

// round-to-nearest-even fp32 -> bf16 bits
__device__ __forceinline__ u16 bf_rne(float f) {
    unsigned u = __float_as_uint(f);
    return (u16)((u + 0x7FFF + ((u >> 16) & 1)) >> 16);
}
__device__ __forceinline__ float bf_val(u16 h) {
    return __uint_as_float((unsigned)h << 16);
}
// split f into hi + lo bf16 (hi+lo ~= f to ~2^-17 rel)
__device__ __forceinline__ void bf_split(float f, u16& hi, u16& lo) {
    hi = bf_rne(f);
    lo = bf_rne(f - bf_val(hi));
}

// async global->LDS, 16 B per lane; LDS dest = wave-uniform base + lane*16
__device__ __forceinline__ void async16(const u16* g, u16* l) {
    __builtin_amdgcn_global_load_lds(
        (const __attribute__((address_space(1))) void*)g,
        (__attribute__((address_space(3))) void*)l,
        16, 0, 0);
}

// ---------------------------------------------------------------------------
// Embedding + sinusoidal positional encoding -> Xf (fp32) and XH/XL (split)
// ---------------------------------------------------------------------------
__global__ __launch_bounds__(256)
void embed_pos_kernel(const int* __restrict__ idx,
                      const float* __restrict__ emb,
                      float* __restrict__ xf,
                      u16* __restrict__ xh, u16* __restrict__ xl)
{
    int gid = blockIdx.x * blockDim.x + threadIdx.x;   // over T_TOK*DM
    if (gid >= T_TOK * DM) return;
    int dcol = gid & (DM - 1);
    int tok  = gid >> 10;
    int t    = tok & (SEQ - 1);
    int id = idx[tok];
    if (id >= VOCAB || id < 0) id = UNK_IDX;
    int p = dcol >> 1;
    float power = (float)p / 512.0f;
    float denom = powf(10000.0f, power);
    float ang = (float)t / denom;
    float pe = (dcol & 1) ? cosf(ang) : sinf(ang);
    float v = emb[(long long)id * DM + dcol] + pe;
    xf[gid] = v;
    u16 h, l; bf_split(v, h, l);
    xh[gid] = h; xl[gid] = l;
}

// ---------------------------------------------------------------------------
// Weight transpose + split: in [K,N] fp32 -> outH/outL [Npad,K] bf16 bits
// ---------------------------------------------------------------------------
__global__ __launch_bounds__(256)
void transpose_split_kernel(const float* __restrict__ in,
                            u16* __restrict__ outH, u16* __restrict__ outL,
                            int K, int N, int Npad)
{
    __shared__ float t[32][33];
    int n0 = blockIdx.x * 32, k0 = blockIdx.y * 32;
    int tx = threadIdx.x & 31, ty = threadIdx.x >> 5;   // ty 0..7
#pragma unroll
    for (int i = 0; i < 4; i++) {
        int k = k0 + ty + i * 8, n = n0 + tx;
        t[ty + i * 8][tx] = (k < K && n < N) ? in[(long long)k * N + n] : 0.f;
    }
    __syncthreads();
#pragma unroll
    for (int i = 0; i < 4; i++) {
        int n = n0 + ty + i * 8, k = k0 + tx;
        if (n < Npad && k < K) {
            u16 h, l; bf_split(t[tx][ty + i * 8], h, l);
            outH[(long long)n * K + k] = h;
            outL[(long long)n * K + k] = l;
        }
    }
}

// pad b4 [75] -> b4p [128]
__global__ __launch_bounds__(128)
void pad_bias_kernel(const float* __restrict__ b, float* __restrict__ bp)
{
    int i = threadIdx.x;
    bp[i] = (i < NCAT) ? b[i] : 0.f;
}

// ---------------------------------------------------------------------------
// Split-bf16 MFMA NT GEMM (emulated fp32), software-pipelined dbuf K-loop.
//   C = scale*(A @ B^T) + bias [,relu]; A=Ahi+Alo [M,ld], B=Bhi+Blo [N,ld],
//   contraction over K columns starting at (z*sA / z*sB element offsets).
//   3 MFMA passes/frag: al*bh + ah*bl + ah*bh. fp32 accumulate.
//   128x128 tile, BK=32, 256 thr = 4 waves (2x2), 4x4 16x16x32 MFMA/wave.
//   LDS: 4 tensors x 2 buffers x 8 KB = 64 KB; XOR chunk swizzle (row&3)
//   keeps global_load_lds lane-contiguity AND makes ds_read_b128 2-way clean.
// OUT_MODE: 0 = fp32 [M,N] at Chi + z*sC; 1 = split bf16 pair [M,N];
//           2 = split bf16 KV-transposed [b][n][t], b=row>>11, t=row&2047.
// ---------------------------------------------------------------------------
template<int OUT_MODE>
__global__ __launch_bounds__(256)
void gemm3_nt(const u16* __restrict__ Ahi, const u16* __restrict__ Alo,
              const u16* __restrict__ Bhi, const u16* __restrict__ Blo,
              const float* __restrict__ bias,
              void* __restrict__ Chi, void* __restrict__ Clo,
              int M, int N, int K, int ld,
              long long sA, long long sB, long long sC,
              float scale, int do_relu)
{
    Ahi += (long long)blockIdx.z * sA;  Alo += (long long)blockIdx.z * sA;
    Bhi += (long long)blockIdx.z * sB;  Blo += (long long)blockIdx.z * sB;
    const int tid  = threadIdx.x;
    const int lane = tid & 63;
    const int w    = tid >> 6;          // wave 0..3
    const int wm   = w >> 1, wn = w & 1;
    const long long row0 = (long long)blockIdx.y * 128;
    const long long col0 = (long long)blockIdx.x * 128;

    // 4 tensors x 2 buffers x 4096 u16 = 64 KB
    __shared__ u16 smem[8 * 4096];
    u16* const AHs = smem;              // [2][4096]
    u16* const ALs = smem + 2 * 4096;
    u16* const BHs = smem + 4 * 4096;
    u16* const BLs = smem + 6 * 4096;

    f32x4 acc[4][4];
    const f32x4 zero = {0.f, 0.f, 0.f, 0.f};
#pragma unroll
    for (int i = 0; i < 4; i++)
#pragma unroll
        for (int j = 0; j < 4; j++) acc[i][j] = zero;

    const int ldrow = lane >> 2;                                  // staging row in 16-row chunk
    const int swcol = (((lane & 3) << 3)) ^ ((ldrow & 3) << 3);   // swizzled source col (elems)
    const int fr    = lane & 15;                                  // fragment row
    const int kk8   = (lane >> 4) << 3;                           // fragment k offset

    const int KT = K / 32;

#define ISSUE(k0, buf)                                                         \
    {                                                                          \
        _Pragma("unroll")                                                      \
        for (int it = 0; it < 2; ++it) {                                       \
            int rb = (it * 4 + w) * 16;                                        \
            long long ao = (row0 + rb + ldrow) * (long long)ld + (k0) + swcol; \
            long long bo = (col0 + rb + ldrow) * (long long)ld + (k0) + swcol; \
            u16* dst = (u16*)((buf) * 4096) ;                                  \
            (void)dst;                                                         \
            async16(Ahi + ao, AHs + (buf) * 4096 + rb * 32);                   \
            async16(Alo + ao, ALs + (buf) * 4096 + rb * 32);                   \
            async16(Bhi + bo, BHs + (buf) * 4096 + rb * 32);                   \
            async16(Blo + bo, BLs + (buf) * 4096 + rb * 32);                   \
        }                                                                      \
    }

    ISSUE(0, 0);
    for (int kt = 0; kt < KT; ++kt) {
        const int cur = kt & 1;
        // barrier (compiler drains vmcnt first): cur buffer ready, and all
        // waves are done reading the buffer we are about to overwrite.
        __syncthreads();
        if (kt + 1 < KT) ISSUE((kt + 1) * 32, cur ^ 1);

        short8 ah[4], al[4], bh[4], bl[4];
#pragma unroll
        for (int i = 0; i < 4; ++i) {
            int r   = wm * 64 + i * 16 + fr;
            int off = cur * 4096 + r * 32 + (kk8 ^ ((r & 3) << 3));
            ah[i] = *(const short8*)(AHs + off);
            al[i] = *(const short8*)(ALs + off);
        }
#pragma unroll
        for (int j = 0; j < 4; ++j) {
            int r   = wn * 64 + j * 16 + fr;
            int off = cur * 4096 + r * 32 + (kk8 ^ ((r & 3) << 3));
            bh[j] = *(const short8*)(BHs + off);
            bl[j] = *(const short8*)(BLs + off);
        }
#pragma unroll
        for (int i = 0; i < 4; ++i)
#pragma unroll
            for (int j = 0; j < 4; ++j) {
                acc[i][j] = __builtin_amdgcn_mfma_f32_16x16x32_bf16(al[i], bh[j], acc[i][j], 0, 0, 0);
                acc[i][j] = __builtin_amdgcn_mfma_f32_16x16x32_bf16(ah[i], bl[j], acc[i][j], 0, 0, 0);
                acc[i][j] = __builtin_amdgcn_mfma_f32_16x16x32_bf16(ah[i], bh[j], acc[i][j], 0, 0, 0);
            }
    }
#undef ISSUE

    // Epilogue. C/D layout: col = lane&15, row = (lane>>4)*4 + reg
    const int qr = (lane >> 4) * 4;
    const int lc = lane & 15;
#pragma unroll
    for (int i = 0; i < 4; ++i) {
#pragma unroll
        for (int j = 0; j < 4; ++j) {
            long long gc = col0 + wn * 64 + j * 16 + lc;
            float bv = bias ? bias[gc] : 0.f;
            if (OUT_MODE == 2) {
                long long gr = row0 + wm * 64 + i * 16 + qr;  // 4 consecutive tokens
                int b  = (int)(gr >> 11);
                int tl = (int)(gr & (SEQ - 1));
                us4 ph, pl;
#pragma unroll
                for (int r = 0; r < 4; ++r) {
                    float f = acc[i][j][r] * scale + bv;
                    if (do_relu) f = fmaxf(f, 0.f);
                    u16 h, l; bf_split(f, h, l);
                    ph.s[r] = h; pl.s[r] = l;
                }
                long long base = (long long)b * N * SEQ + gc * SEQ + tl;
                *(us4*)((u16*)Chi + base) = ph;
                *(us4*)((u16*)Clo + base) = pl;
            } else if (OUT_MODE == 1) {
                u16* CH = (u16*)Chi + blockIdx.z * sC;
                u16* CL = (u16*)Clo + blockIdx.z * sC;
#pragma unroll
                for (int r = 0; r < 4; ++r) {
                    long long gr = row0 + wm * 64 + i * 16 + qr + r;
                    float f = acc[i][j][r] * scale + bv;
                    if (do_relu) f = fmaxf(f, 0.f);
                    u16 h, l; bf_split(f, h, l);
                    CH[gr * N + gc] = h;
                    CL[gr * N + gc] = l;
                }
            } else {
                float* C = (float*)Chi + blockIdx.z * sC;
#pragma unroll
                for (int r = 0; r < 4; ++r) {
                    long long gr = row0 + wm * 64 + i * 16 + qr + r;
                    float f = acc[i][j][r] * scale + bv;
                    if (do_relu) f = fmaxf(f, 0.f);
                    C[gr * N + gc] = f;
                }
            }
        }
    }
}

// ---------------------------------------------------------------------------
// out = s0 + s1 + bias (split-K reduce for FF2), float4-vectorized
// n4 = total elems/4, ncol = row width (1024)
// ---------------------------------------------------------------------------
__global__ __launch_bounds__(256)
void reduce2_bias_kernel(const float* __restrict__ s0, const float* __restrict__ s1,
                         const float* __restrict__ bias, float* __restrict__ out,
                         int n4)
{
    int i = blockIdx.x * blockDim.x + threadIdx.x;
    if (i >= n4) return;
    float4 a = ((const float4*)s0)[i];
    float4 b = ((const float4*)s1)[i];
    int c4 = (i * 4) & (DM - 1);
    float4 bb = *(const float4*)(bias + c4);
    float4 r;
    r.x = a.x + b.x + bb.x;
    r.y = a.y + b.y + bb.y;
    r.z = a.z + b.z + bb.z;
    r.w = a.w + b.w + bb.w;
    ((float4*)out)[i] = r;
}

// ---------------------------------------------------------------------------
// LN(X + Y) * g + b over DM=1024; writes fp32 (nullable) and split pair
// ---------------------------------------------------------------------------
__global__ __launch_bounds__(256)
void add_ln_kernel(const float* __restrict__ X, const float* __restrict__ Y,
                   const float* __restrict__ g, const float* __restrict__ b,
                   float* __restrict__ outf,
                   u16* __restrict__ outh, u16* __restrict__ outl)
{
    int row = blockIdx.x;
    int tid = threadIdx.x;
    const float* xr = X + (long long)row * DM;
    const float* yr = Y + (long long)row * DM;
    float v[4];
    float s = 0.f, s2 = 0.f;
#pragma unroll
    for (int i = 0; i < 4; i++) {
        int c = tid + i * 256;
        v[i] = xr[c] + yr[c];
        s  += v[i];
        s2 += v[i] * v[i];
    }
#pragma unroll
    for (int o = 1; o < 64; o <<= 1) {
        s  += __shfl_xor(s,  o, 64);
        s2 += __shfl_xor(s2, o, 64);
    }
    __shared__ float rs[4], rs2[4], stats[2];
    int wid = tid >> 6;
    if ((tid & 63) == 0) { rs[wid] = s; rs2[wid] = s2; }
    __syncthreads();
    if (tid == 0) {
        float S  = rs[0] + rs[1] + rs[2] + rs[3];
        float S2 = rs2[0] + rs2[1] + rs2[2] + rs2[3];
        float mean = S / (float)DM;
        float var  = S2 / (float)DM - mean * mean;   // biased var == jnp.var
        stats[0] = mean;
        stats[1] = rsqrtf(var + EPS);
    }
    __syncthreads();
    float mean = stats[0], rstd = stats[1];
#pragma unroll
    for (int i = 0; i < 4; i++) {
        int c = tid + i * 256;
        float o = (v[i] - mean) * rstd * g[c] + b[c];
        if (outf) outf[(long long)row * DM + c] = o;
        u16 h, l; bf_split(o, h, l);
        outh[(long long)row * DM + c] = h;
        outl[(long long)row * DM + c] = l;
    }
}

// ---------------------------------------------------------------------------
// out[row,:] = sigmoid(LN75(L[row,0:75]) * g + b); L leading dim 128
// ---------------------------------------------------------------------------
__global__ __launch_bounds__(64)
void ln75_sigmoid_kernel(const float* __restrict__ L,
                         const float* __restrict__ g, const float* __restrict__ b,
                         float* __restrict__ out)
{
    int row = blockIdx.x;
    int t   = threadIdx.x;
    const float* lr = L + (long long)row * 128;
    float e0 = (t < NCAT) ? lr[t] : 0.f;
    float e1 = (t + 64 < NCAT) ? lr[t + 64] : 0.f;
    float s  = e0 + e1;
    float s2 = e0 * e0 + e1 * e1;
#pragma unroll
    for (int o = 1; o < 64; o <<= 1) {
        s  += __shfl_xor(s,  o, 64);
        s2 += __shfl_xor(s2, o, 64);
    }
    float mean = s / (float)NCAT;
    float var  = s2 / (float)NCAT - mean * mean;
    float rstd = rsqrtf(var + EPS);
    if (t < NCAT) {
        float z = (e0 - mean) * rstd * g[t] + b[t];
        out[(long long)row * NCAT + t] = 1.f / (1.f + expf(-z));
    }
    if (t + 64 < NCAT) {
        float z = (e1 - mean) * rstd * g[t + 64] + b[t + 64];
        out[(long long)row * NCAT + t + 64] = 1.f / (1.f + expf(-z));
    }
}

// ---------------------------------------------------------------------------
// Orchestration. Attention reassociated: (QK^T/8)V == Q @ (K^T V * 0.125).
// Region reuse identical to R3; FF2 split-K=2 slices live in R_F (ktv dead).
// ---------------------------------------------------------------------------
extern "C" void kernel_launch(void* const* d_in, const int* in_sizes, int n_in,
                              void* d_out, int out_size, void* d_ws, size_t ws_size,
                              hipStream_t stream)
{
    const int*   idx = (const int*)  d_in[0];
    const float* emb = (const float*)d_in[1];
    const float* Wq  = (const float*)d_in[2];
    const float* bq  = (const float*)d_in[3];
    const float* Wk  = (const float*)d_in[4];
    const float* bk  = (const float*)d_in[5];
    const float* Wv  = (const float*)d_in[6];
    const float* bv  = (const float*)d_in[7];
    const float* Wu  = (const float*)d_in[8];
    const float* bu  = (const float*)d_in[9];
    const float* g1  = (const float*)d_in[10];
    const float* be1 = (const float*)d_in[11];
    const float* W1  = (const float*)d_in[12];
    const float* b1  = (const float*)d_in[13];
    const float* W2  = (const float*)d_in[14];
    const float* b2  = (const float*)d_in[15];
    const float* g2  = (const float*)d_in[16];
    const float* be2 = (const float*)d_in[17];
    const float* W3  = (const float*)d_in[18];
    const float* b3  = (const float*)d_in[19];
    const float* W4  = (const float*)d_in[20];
    const float* b4  = (const float*)d_in[21];
    const float* g3  = (const float*)d_in[22];
    const float* be3 = (const float*)d_in[23];

    const long long TD  = (long long)T_TOK * DM;       // 16.78M
    char* p = (char*)d_ws;
    char* R_A = p; p += TD * 4;
    char* R_B = p; p += TD * 4;
    char* R_C = p; p += TD * 4;
    char* R_D = p; p += TD * 4;
    char* R_E = p; p += TD * 4;
    char* R_F = p; p += (long long)NB * DM * DM * 4;   // 32 MB
    char* R_G = p; p += (long long)T_TOK * 128 * 4;    // 8 MB
    u16* WqH = (u16*)p; p += DM*DM*2;     u16* WqL = (u16*)p; p += DM*DM*2;
    u16* WkH = (u16*)p; p += DM*DM*2;     u16* WkL = (u16*)p; p += DM*DM*2;
    u16* WvH = (u16*)p; p += DM*DM*2;     u16* WvL = (u16*)p; p += DM*DM*2;
    u16* WuH = (u16*)p; p += DM*DM*2;     u16* WuL = (u16*)p; p += DM*DM*2;
    u16* W1H = (u16*)p; p += (long long)FFD*DM*2;  u16* W1L = (u16*)p; p += (long long)FFD*DM*2;
    u16* W2H = (u16*)p; p += (long long)DM*FFD*2;  u16* W2L = (u16*)p; p += (long long)DM*FFD*2;
    u16* W3H = (u16*)p; p += 512*DM*2;    u16* W3L = (u16*)p; p += 512*DM*2;
    u16* W4H = (u16*)p; p += 128*512*2;   u16* W4L = (u16*)p; p += 128*512*2;
    float* b4p = (float*)p; p += 128*4;

    float* Xf   = (float*)R_A;
    float* ffo  = (float*)R_A;
    u16*   XH   = (u16*)R_B;              u16* XL   = XH + TD;
    u16*   attnH= (u16*)R_B;              u16* attnL= attnH + TD;
    u16*   h2H  = (u16*)R_B;              u16* h2L  = h2H + TD;
    u16*   QH   = (u16*)R_C;              u16* QL   = QH + TD;
    u16*   h1H  = (u16*)R_C;              u16* h1L  = h1H + TD;
    u16*   KtH  = (u16*)R_D;              u16* KtL  = KtH + TD;
    float* u    = (float*)R_D;
    u16*   f1H  = (u16*)R_D;              u16* f1L  = f1H + (long long)4096*FFD;
    u16*   VtH  = (u16*)R_E;              u16* VtL  = VtH + TD;
    float* h1f  = (float*)R_E;
    u16*   ktvH = (u16*)R_F;              u16* ktvL = ktvH + (long long)NB*DM*DM;
    float* slc  = (float*)R_F;            // FF2 slices: 2 x [4096,1024] fp32 = 32 MB
    u16*   l1H  = (u16*)R_F;              u16* l1L  = l1H + (long long)T_TOK*512;
    float* LOG  = (float*)R_G;
    float* out  = (float*)d_out;

    dim3 blk(256);

    // ---- weight transpose + split ---------------------------------------
    transpose_split_kernel<<<dim3(32, 32),  blk, 0, stream>>>(Wq, WqH, WqL, DM, DM, DM);
    transpose_split_kernel<<<dim3(32, 32),  blk, 0, stream>>>(Wk, WkH, WkL, DM, DM, DM);
    transpose_split_kernel<<<dim3(32, 32),  blk, 0, stream>>>(Wv, WvH, WvL, DM, DM, DM);
    transpose_split_kernel<<<dim3(32, 32),  blk, 0, stream>>>(Wu, WuH, WuL, DM, DM, DM);
    transpose_split_kernel<<<dim3(128, 32), blk, 0, stream>>>(W1, W1H, W1L, DM, FFD, FFD);
    transpose_split_kernel<<<dim3(32, 128), blk, 0, stream>>>(W2, W2H, W2L, FFD, DM, DM);
    transpose_split_kernel<<<dim3(16, 32),  blk, 0, stream>>>(W3, W3H, W3L, DM, 512, 512);
    transpose_split_kernel<<<dim3(4, 16),   blk, 0, stream>>>(W4, W4H, W4L, 512, NCAT, 128);
    pad_bias_kernel<<<1, 128, 0, stream>>>(b4, b4p);

    // ---- x = emb[idx] + pos ---------------------------------------------
    embed_pos_kernel<<<(T_TOK * DM + 255) / 256, blk, 0, stream>>>(idx, emb, Xf, XH, XL);

    // ---- QKV: Q normal; K,V transposed [b][dm][seq] ---------------------
    gemm3_nt<1><<<dim3(8, 128, 1), blk, 0, stream>>>(XH, XL, WqH, WqL, bq, QH, QL,
        T_TOK, DM, DM, DM, 0, 0, 0, 1.f, 0);
    gemm3_nt<2><<<dim3(8, 128, 1), blk, 0, stream>>>(XH, XL, WkH, WkL, bk, KtH, KtL,
        T_TOK, DM, DM, DM, 0, 0, 0, 1.f, 0);
    gemm3_nt<2><<<dim3(8, 128, 1), blk, 0, stream>>>(XH, XL, WvH, WvL, bv, VtH, VtL,
        T_TOK, DM, DM, DM, 0, 0, 0, 1.f, 0);

    // ---- KTV^T[b] = NT(Vt[b], Kt[b]) * 0.125   [8][1024][1024] ----------
    gemm3_nt<1><<<dim3(8, 8, NB), blk, 0, stream>>>(VtH, VtL, KtH, KtL, nullptr, ktvH, ktvL,
        DM, DM, SEQ, SEQ, (long long)DM * SEQ, (long long)DM * SEQ, (long long)DM * DM, 0.125f, 0);

    // ---- attn[b] = NT(Q[b], KTV^T[b])   [8][2048][1024] -----------------
    gemm3_nt<1><<<dim3(8, 16, NB), blk, 0, stream>>>(QH, QL, ktvH, ktvL, nullptr, attnH, attnL,
        SEQ, DM, DM, DM, (long long)SEQ * DM, (long long)DM * DM, (long long)SEQ * DM, 1.f, 0);

    // ---- u = attn @ Wu + bu  (fp32) -------------------------------------
    gemm3_nt<0><<<dim3(8, 128, 1), blk, 0, stream>>>(attnH, attnL, WuH, WuL, bu, u, nullptr,
        T_TOK, DM, DM, DM, 0, 0, 0, 1.f, 0);

    // ---- h1 = LN(x + u): fp32 + split -----------------------------------
    add_ln_kernel<<<T_TOK, blk, 0, stream>>>(Xf, u, g1, be1, h1f, h1H, h1L);

    // ---- FFN chunked over M by 4096; FF2 split-K=2 + fused reduce -------
    for (int c = 0; c < 4; c++) {
        const u16* h1Hc = h1H + (long long)c * 4096 * DM;
        const u16* h1Lc = h1L + (long long)c * 4096 * DM;
        float*     ffoc = ffo + (long long)c * 4096 * DM;
        gemm3_nt<1><<<dim3(32, 32, 1), blk, 0, stream>>>(h1Hc, h1Lc, W1H, W1L, b1, f1H, f1L,
            4096, FFD, DM, DM, 0, 0, 0, 1.f, 1);
        // slices: z in {0,1}, K-slice 2048 (offset z*2048), out slice z*4096*DM
        gemm3_nt<0><<<dim3(8, 32, 2), blk, 0, stream>>>(f1H, f1L, W2H, W2L, nullptr, slc, nullptr,
            4096, DM, 2048, FFD, 2048, 2048, (long long)4096 * DM, 1.f, 0);
        reduce2_bias_kernel<<<(4096 * DM / 4 + 255) / 256, blk, 0, stream>>>(
            slc, slc + (long long)4096 * DM, b2, ffoc, 4096 * DM / 4);
    }

    // ---- h2 = LN(h1 + ffo): split only ----------------------------------
    add_ln_kernel<<<T_TOK, blk, 0, stream>>>(h1f, ffo, g2, be2, nullptr, h2H, h2L);

    // ---- head: l1 = relu(h2@W3+b3) split; LOG = l1@W4p + b4p (N=128) ----
    gemm3_nt<1><<<dim3(4, 128, 1), blk, 0, stream>>>(h2H, h2L, W3H, W3L, b3, l1H, l1L,
        T_TOK, 512, DM, DM, 0, 0, 0, 1.f, 1);
    gemm3_nt<0><<<dim3(1, 128, 1), blk, 0, stream>>>(l1H, l1L, W4H, W4L, b4p, LOG, nullptr,
        T_TOK, 128, 512, 512, 0, 0, 0, 1.f, 0);

    // ---- out = sigmoid(LN75(logits)) ------------------------------------
    ln75_sigmoid_kernel<<<T_TOK, 64, 0, stream>>>(LOG, g3, be3, out);
}

// Round 5
// 1253.463 us; speedup vs baseline: 6.1339x; 1.7237x over previous
//
#include <hip/hip_runtime.h>
#include <hip/hip_fp16.h>
#include <math.h>

// Problem constants
#define DM    1024
#define FFD   4096
#define VOCAB 32000
#define NCAT  75
#define UNK_IDX 1
#define EPS   1e-5f
#define NB    8
#define SEQ   2048
#define T_TOK (NB*SEQ)   // 16384 tokens

using u16   = unsigned short;
using half_t = _Float16;
using half8 = __attribute__((ext_vector_type(8))) _Float16;  // MFMA A/B frag (4 VGPRs)
using f32x4 = __attribute__((ext_vector_type(4))) float;     // MFMA C/D frag

struct alignas(8) h4 { half_t s[4]; };

// async global->LDS, 16 B per lane; LDS dest = wave-uniform base + lane*16
__device__ __forceinline__ void async16(const half_t* g, half_t* l) {
    __builtin_amdgcn_global_load_lds(
        (const __attribute__((address_space(1))) void*)g,
        (__attribute__((address_space(3))) void*)l,
        16, 0, 0);
}

// ---------------------------------------------------------------------------
// Embedding + sinusoidal positional encoding -> Xf (fp32) and Xh (fp16)
// ---------------------------------------------------------------------------
__global__ __launch_bounds__(256)
void embed_pos_kernel(const int* __restrict__ idx,
                      const float* __restrict__ emb,
                      float* __restrict__ xf, half_t* __restrict__ xh)
{
    int gid = blockIdx.x * blockDim.x + threadIdx.x;   // over T_TOK*DM
    if (gid >= T_TOK * DM) return;
    int dcol = gid & (DM - 1);
    int tok  = gid >> 10;
    int t    = tok & (SEQ - 1);
    int id = idx[tok];
    if (id >= VOCAB || id < 0) id = UNK_IDX;
    int p = dcol >> 1;
    float power = (float)p / 512.0f;
    float denom = powf(10000.0f, power);
    float ang = (float)t / denom;
    float pe = (dcol & 1) ? cosf(ang) : sinf(ang);
    float v = emb[(long long)id * DM + dcol] + pe;
    xf[gid] = v;
    xh[gid] = (half_t)v;
}

// ---------------------------------------------------------------------------
// Weight transpose + fp32->fp16: in [K,N] fp32 -> out [Npad,K] fp16
// rows n in [N,Npad) zero-filled (pads W4 75 -> 128).
// ---------------------------------------------------------------------------
__global__ __launch_bounds__(256)
void transpose_h_kernel(const float* __restrict__ in, half_t* __restrict__ out,
                        int K, int N, int Npad)
{
    __shared__ float t[32][33];
    int n0 = blockIdx.x * 32, k0 = blockIdx.y * 32;
    int tx = threadIdx.x & 31, ty = threadIdx.x >> 5;   // ty 0..7
#pragma unroll
    for (int i = 0; i < 4; i++) {
        int k = k0 + ty + i * 8, n = n0 + tx;
        t[ty + i * 8][tx] = (k < K && n < N) ? in[(long long)k * N + n] : 0.f;
    }
    __syncthreads();
#pragma unroll
    for (int i = 0; i < 4; i++) {
        int n = n0 + ty + i * 8, k = k0 + tx;
        if (n < Npad && k < K)
            out[(long long)n * K + k] = (half_t)t[tx][ty + i * 8];
    }
}

// pad b4 [75] -> b4p [128]
__global__ __launch_bounds__(128)
void pad_bias_kernel(const float* __restrict__ b, float* __restrict__ bp)
{
    int i = threadIdx.x;
    bp[i] = (i < NCAT) ? b[i] : 0.f;
}

// ---------------------------------------------------------------------------
// fp16 MFMA NT GEMM, software-pipelined dbuf K-loop (m97 shape).
//   C = scale*(A @ B^T) + bias [,relu]; A [M,ld], B [N,ld] fp16, fp32 acc.
//   128x128 tile, BK=32, 256 thr = 4 waves (2x2), 4x4 16x16x32 MFMA/wave.
//   LDS: 2 tensors x 2 buffers x 8 KB = 32 KB; XOR chunk swizzle on (row&3).
// OUT_MODE: 0 = fp32 [M,N] at C + z*sC; 1 = fp16 [M,N];
//           2 = fp16 KV-transposed [b][n][t], b=row>>11, t=row&2047.
// ---------------------------------------------------------------------------
template<int OUT_MODE>
__global__ __launch_bounds__(256)
void gemm_nt(const half_t* __restrict__ A, const half_t* __restrict__ B,
             const float* __restrict__ bias, void* __restrict__ Cout,
             int M, int N, int K, int ld,
             long long sA, long long sB, long long sC,
             float scale, int do_relu)
{
    A += (long long)blockIdx.z * sA;
    B += (long long)blockIdx.z * sB;
    const int tid  = threadIdx.x;
    const int lane = tid & 63;
    const int w    = tid >> 6;          // wave 0..3
    const int wm   = w >> 1, wn = w & 1;
    const long long row0 = (long long)blockIdx.y * 128;
    const long long col0 = (long long)blockIdx.x * 128;

    // 2 tensors x 2 buffers x 4096 halves = 32 KB
    __shared__ half_t smem[4 * 4096];
    half_t* const As = smem;             // [2][4096]
    half_t* const Bs = smem + 2 * 4096;

    f32x4 acc[4][4];
    const f32x4 zero = {0.f, 0.f, 0.f, 0.f};
#pragma unroll
    for (int i = 0; i < 4; i++)
#pragma unroll
        for (int j = 0; j < 4; j++) acc[i][j] = zero;

    const int ldrow = lane >> 2;                                  // staging row in 16-row chunk
    const int swcol = (((lane & 3) << 3)) ^ ((ldrow & 3) << 3);   // swizzled source col (elems)
    const int fr    = lane & 15;                                  // fragment row
    const int kk8   = (lane >> 4) << 3;                           // fragment k offset

    const int KT = K / 32;

#define ISSUE(k0, buf)                                                         \
    {                                                                          \
        _Pragma("unroll")                                                      \
        for (int it = 0; it < 2; ++it) {                                       \
            int rb = (it * 4 + w) * 16;                                        \
            long long ao = (row0 + rb + ldrow) * (long long)ld + (k0) + swcol; \
            long long bo = (col0 + rb + ldrow) * (long long)ld + (k0) + swcol; \
            async16(A + ao, As + (buf) * 4096 + rb * 32);                      \
            async16(B + bo, Bs + (buf) * 4096 + rb * 32);                      \
        }                                                                      \
    }

    ISSUE(0, 0);
    for (int kt = 0; kt < KT; ++kt) {
        const int cur = kt & 1;
        __syncthreads();                 // cur buffer ready; prev consumers done
        if (kt + 1 < KT) ISSUE((kt + 1) * 32, cur ^ 1);

        half8 af[4], bf[4];
#pragma unroll
        for (int i = 0; i < 4; ++i) {
            int r   = wm * 64 + i * 16 + fr;
            int off = cur * 4096 + r * 32 + (kk8 ^ ((r & 3) << 3));
            af[i] = *(const half8*)(As + off);
        }
#pragma unroll
        for (int j = 0; j < 4; ++j) {
            int r   = wn * 64 + j * 16 + fr;
            int off = cur * 4096 + r * 32 + (kk8 ^ ((r & 3) << 3));
            bf[j] = *(const half8*)(Bs + off);
        }
#pragma unroll
        for (int i = 0; i < 4; ++i)
#pragma unroll
            for (int j = 0; j < 4; ++j)
                acc[i][j] = __builtin_amdgcn_mfma_f32_16x16x32_f16(
                    af[i], bf[j], acc[i][j], 0, 0, 0);
    }
#undef ISSUE

    // Epilogue. C/D layout: col = lane&15, row = (lane>>4)*4 + reg
    const int qr = (lane >> 4) * 4;
    const int lc = lane & 15;
#pragma unroll
    for (int i = 0; i < 4; ++i) {
#pragma unroll
        for (int j = 0; j < 4; ++j) {
            long long gc = col0 + wn * 64 + j * 16 + lc;
            float bv = bias ? bias[gc] : 0.f;
            if (OUT_MODE == 2) {
                long long gr = row0 + wm * 64 + i * 16 + qr;  // 4 consecutive tokens
                int b  = (int)(gr >> 11);
                int tl = (int)(gr & (SEQ - 1));
                h4 pk;
#pragma unroll
                for (int r = 0; r < 4; ++r) {
                    float f = acc[i][j][r] * scale + bv;
                    if (do_relu) f = fmaxf(f, 0.f);
                    pk.s[r] = (half_t)f;
                }
                half_t* C = (half_t*)Cout;
                *(h4*)(C + (long long)b * N * SEQ + gc * SEQ + tl) = pk;
            } else if (OUT_MODE == 1) {
                half_t* C = (half_t*)Cout + blockIdx.z * sC;
#pragma unroll
                for (int r = 0; r < 4; ++r) {
                    long long gr = row0 + wm * 64 + i * 16 + qr + r;
                    float f = acc[i][j][r] * scale + bv;
                    if (do_relu) f = fmaxf(f, 0.f);
                    C[gr * N + gc] = (half_t)f;
                }
            } else {
                float* C = (float*)Cout + blockIdx.z * sC;
#pragma unroll
                for (int r = 0; r < 4; ++r) {
                    long long gr = row0 + wm * 64 + i * 16 + qr + r;
                    float f = acc[i][j][r] * scale + bv;
                    if (do_relu) f = fmaxf(f, 0.f);
                    C[gr * N + gc] = f;
                }
            }
        }
    }
}

// ---------------------------------------------------------------------------
// out = s0 + s1 + bias (split-K reduce for FF2), float4-vectorized
// ---------------------------------------------------------------------------
__global__ __launch_bounds__(256)
void reduce2_bias_kernel(const float* __restrict__ s0, const float* __restrict__ s1,
                         const float* __restrict__ bias, float* __restrict__ out,
                         int n4)
{
    int i = blockIdx.x * blockDim.x + threadIdx.x;
    if (i >= n4) return;
    float4 a = ((const float4*)s0)[i];
    float4 b = ((const float4*)s1)[i];
    int c4 = (i * 4) & (DM - 1);
    float4 bb = *(const float4*)(bias + c4);
    float4 r;
    r.x = a.x + b.x + bb.x;
    r.y = a.y + b.y + bb.y;
    r.z = a.z + b.z + bb.z;
    r.w = a.w + b.w + bb.w;
    ((float4*)out)[i] = r;
}

// ---------------------------------------------------------------------------
// LN(X + Y) * g + b over DM=1024; writes fp32 (nullable) and fp16
// ---------------------------------------------------------------------------
__global__ __launch_bounds__(256)
void add_ln_kernel(const float* __restrict__ X, const float* __restrict__ Y,
                   const float* __restrict__ g, const float* __restrict__ b,
                   float* __restrict__ outf, half_t* __restrict__ outh)
{
    int row = blockIdx.x;
    int tid = threadIdx.x;
    const float* xr = X + (long long)row * DM;
    const float* yr = Y + (long long)row * DM;
    float v[4];
    float s = 0.f, s2 = 0.f;
#pragma unroll
    for (int i = 0; i < 4; i++) {
        int c = tid + i * 256;
        v[i] = xr[c] + yr[c];
        s  += v[i];
        s2 += v[i] * v[i];
    }
#pragma unroll
    for (int o = 1; o < 64; o <<= 1) {
        s  += __shfl_xor(s,  o, 64);
        s2 += __shfl_xor(s2, o, 64);
    }
    __shared__ float rs[4], rs2[4], stats[2];
    int wid = tid >> 6;
    if ((tid & 63) == 0) { rs[wid] = s; rs2[wid] = s2; }
    __syncthreads();
    if (tid == 0) {
        float S  = rs[0] + rs[1] + rs[2] + rs[3];
        float S2 = rs2[0] + rs2[1] + rs2[2] + rs2[3];
        float mean = S / (float)DM;
        float var  = S2 / (float)DM - mean * mean;   // biased var == jnp.var
        stats[0] = mean;
        stats[1] = rsqrtf(var + EPS);
    }
    __syncthreads();
    float mean = stats[0], rstd = stats[1];
#pragma unroll
    for (int i = 0; i < 4; i++) {
        int c = tid + i * 256;
        float o = (v[i] - mean) * rstd * g[c] + b[c];
        if (outf) outf[(long long)row * DM + c] = o;
        outh[(long long)row * DM + c] = (half_t)o;
    }
}

// ---------------------------------------------------------------------------
// out[row,:] = sigmoid(LN75(L[row,0:75]) * g + b); L leading dim 128
// ---------------------------------------------------------------------------
__global__ __launch_bounds__(64)
void ln75_sigmoid_kernel(const float* __restrict__ L,
                         const float* __restrict__ g, const float* __restrict__ b,
                         float* __restrict__ out)
{
    int row = blockIdx.x;
    int t   = threadIdx.x;
    const float* lr = L + (long long)row * 128;
    float e0 = (t < NCAT) ? lr[t] : 0.f;
    float e1 = (t + 64 < NCAT) ? lr[t + 64] : 0.f;
    float s  = e0 + e1;
    float s2 = e0 * e0 + e1 * e1;
#pragma unroll
    for (int o = 1; o < 64; o <<= 1) {
        s  += __shfl_xor(s,  o, 64);
        s2 += __shfl_xor(s2, o, 64);
    }
    float mean = s / (float)NCAT;
    float var  = s2 / (float)NCAT - mean * mean;
    float rstd = rsqrtf(var + EPS);
    if (t < NCAT) {
        float z = (e0 - mean) * rstd * g[t] + b[t];
        out[(long long)row * NCAT + t] = 1.f / (1.f + expf(-z));
    }
    if (t + 64 < NCAT) {
        float z = (e1 - mean) * rstd * g[t + 64] + b[t + 64];
        out[(long long)row * NCAT + t + 64] = 1.f / (1.f + expf(-z));
    }
}

// ---------------------------------------------------------------------------
// Orchestration. Attention reassociated: (QK^T/8)V == Q @ (K^T V * 0.125).
// All GEMM operands fp16 (single-pass MFMA), fp32 accumulate, fp32 LN chain.
// Region reuse:
//   R_A 64MB: Xf fp32    -> ffo fp32
//   R_B 32MB: Xh fp16    -> attn fp16 -> h2 fp16
//   R_C 32MB: Q fp16     -> h1 fp16
//   R_D 64MB: Kt fp16    -> u fp32    -> ff1 chunk fp16 [4096,4096]
//   R_E 64MB: Vt fp16    -> h1f fp32
//   R_F 32MB: ktv fp16   -> FF2 slices 2x[4096,1024] fp32 -> l1 fp16
//   R_G  8MB: LOG fp32 [16384,128]
// ---------------------------------------------------------------------------
extern "C" void kernel_launch(void* const* d_in, const int* in_sizes, int n_in,
                              void* d_out, int out_size, void* d_ws, size_t ws_size,
                              hipStream_t stream)
{
    const int*   idx = (const int*)  d_in[0];
    const float* emb = (const float*)d_in[1];
    const float* Wq  = (const float*)d_in[2];
    const float* bq  = (const float*)d_in[3];
    const float* Wk  = (const float*)d_in[4];
    const float* bk  = (const float*)d_in[5];
    const float* Wv  = (const float*)d_in[6];
    const float* bv  = (const float*)d_in[7];
    const float* Wu  = (const float*)d_in[8];
    const float* bu  = (const float*)d_in[9];
    const float* g1  = (const float*)d_in[10];
    const float* be1 = (const float*)d_in[11];
    const float* W1  = (const float*)d_in[12];
    const float* b1  = (const float*)d_in[13];
    const float* W2  = (const float*)d_in[14];
    const float* b2  = (const float*)d_in[15];
    const float* g2  = (const float*)d_in[16];
    const float* be2 = (const float*)d_in[17];
    const float* W3  = (const float*)d_in[18];
    const float* b3  = (const float*)d_in[19];
    const float* W4  = (const float*)d_in[20];
    const float* b4  = (const float*)d_in[21];
    const float* g3  = (const float*)d_in[22];
    const float* be3 = (const float*)d_in[23];

    const long long TD  = (long long)T_TOK * DM;       // 16.78M
    char* p = (char*)d_ws;
    char* R_A = p; p += TD * 4;
    char* R_B = p; p += TD * 2;
    char* R_C = p; p += TD * 2;
    char* R_D = p; p += TD * 4;
    char* R_E = p; p += TD * 4;
    char* R_F = p; p += (long long)NB * DM * DM * 4;   // 32 MB
    char* R_G = p; p += (long long)T_TOK * 128 * 4;    // 8 MB
    half_t* Wqh = (half_t*)p; p += DM*DM*2;
    half_t* Wkh = (half_t*)p; p += DM*DM*2;
    half_t* Wvh = (half_t*)p; p += DM*DM*2;
    half_t* Wuh = (half_t*)p; p += DM*DM*2;
    half_t* W1h = (half_t*)p; p += (long long)FFD*DM*2;
    half_t* W2h = (half_t*)p; p += (long long)DM*FFD*2;
    half_t* W3h = (half_t*)p; p += 512*DM*2;
    half_t* W4h = (half_t*)p; p += 128*512*2;
    float*  b4p = (float*)p;  p += 128*4;

    float*  Xf   = (float*)R_A;
    float*  ffo  = (float*)R_A;
    half_t* Xh   = (half_t*)R_B;
    half_t* attn = (half_t*)R_B;
    half_t* h2h  = (half_t*)R_B;
    half_t* Qh   = (half_t*)R_C;
    half_t* h1h  = (half_t*)R_C;
    half_t* Kt   = (half_t*)R_D;            // [8][1024][2048]
    float*  u    = (float*)R_D;
    half_t* f1h  = (half_t*)R_D;            // [4096,4096] chunk
    half_t* Vt   = (half_t*)R_E;
    float*  h1f  = (float*)R_E;
    half_t* ktv  = (half_t*)R_F;            // [8][1024][1024]
    float*  slc  = (float*)R_F;             // 2 x [4096,1024] fp32
    half_t* l1h  = (half_t*)R_F;            // [16384,512]
    float*  LOG  = (float*)R_G;
    float*  out  = (float*)d_out;

    dim3 blk(256);

    // ---- weight transpose fp32 [K,N] -> fp16 [Npad,K] -------------------
    transpose_h_kernel<<<dim3(32, 32),  blk, 0, stream>>>(Wq, Wqh, DM, DM, DM);
    transpose_h_kernel<<<dim3(32, 32),  blk, 0, stream>>>(Wk, Wkh, DM, DM, DM);
    transpose_h_kernel<<<dim3(32, 32),  blk, 0, stream>>>(Wv, Wvh, DM, DM, DM);
    transpose_h_kernel<<<dim3(32, 32),  blk, 0, stream>>>(Wu, Wuh, DM, DM, DM);
    transpose_h_kernel<<<dim3(128, 32), blk, 0, stream>>>(W1, W1h, DM, FFD, FFD);
    transpose_h_kernel<<<dim3(32, 128), blk, 0, stream>>>(W2, W2h, FFD, DM, DM);
    transpose_h_kernel<<<dim3(16, 32),  blk, 0, stream>>>(W3, W3h, DM, 512, 512);
    transpose_h_kernel<<<dim3(4, 16),   blk, 0, stream>>>(W4, W4h, 512, NCAT, 128);
    pad_bias_kernel<<<1, 128, 0, stream>>>(b4, b4p);

    // ---- x = emb[idx] + pos ---------------------------------------------
    embed_pos_kernel<<<(T_TOK * DM + 255) / 256, blk, 0, stream>>>(idx, emb, Xf, Xh);

    // ---- QKV: Q normal; K,V transposed [b][dm][seq] ---------------------
    gemm_nt<1><<<dim3(8, 128, 1), blk, 0, stream>>>(Xh, Wqh, bq, Qh,
        T_TOK, DM, DM, DM, 0, 0, 0, 1.f, 0);
    gemm_nt<2><<<dim3(8, 128, 1), blk, 0, stream>>>(Xh, Wkh, bk, Kt,
        T_TOK, DM, DM, DM, 0, 0, 0, 1.f, 0);
    gemm_nt<2><<<dim3(8, 128, 1), blk, 0, stream>>>(Xh, Wvh, bv, Vt,
        T_TOK, DM, DM, DM, 0, 0, 0, 1.f, 0);

    // ---- KTV^T[b] = NT(Vt[b], Kt[b]) * 0.125   [8][1024][1024] ----------
    gemm_nt<1><<<dim3(8, 8, NB), blk, 0, stream>>>(Vt, Kt, nullptr, ktv,
        DM, DM, SEQ, SEQ, (long long)DM * SEQ, (long long)DM * SEQ, (long long)DM * DM, 0.125f, 0);

    // ---- attn[b] = NT(Q[b], KTV^T[b])   [8][2048][1024] -----------------
    gemm_nt<1><<<dim3(8, 16, NB), blk, 0, stream>>>(Qh, ktv, nullptr, attn,
        SEQ, DM, DM, DM, (long long)SEQ * DM, (long long)DM * DM, (long long)SEQ * DM, 1.f, 0);

    // ---- u = attn @ Wu + bu  (fp32) -------------------------------------
    gemm_nt<0><<<dim3(8, 128, 1), blk, 0, stream>>>(attn, Wuh, bu, u,
        T_TOK, DM, DM, DM, 0, 0, 0, 1.f, 0);

    // ---- h1 = LN(x + u): fp32 + fp16 ------------------------------------
    add_ln_kernel<<<T_TOK, blk, 0, stream>>>(Xf, u, g1, be1, h1f, h1h);

    // ---- FFN chunked over M by 4096; FF2 split-K=2 + fused reduce -------
    for (int c = 0; c < 4; c++) {
        const half_t* h1c  = h1h + (long long)c * 4096 * DM;
        float*        ffoc = ffo + (long long)c * 4096 * DM;
        gemm_nt<1><<<dim3(32, 32, 1), blk, 0, stream>>>(h1c, W1h, b1, f1h,
            4096, FFD, DM, DM, 0, 0, 0, 1.f, 1);
        gemm_nt<0><<<dim3(8, 32, 2), blk, 0, stream>>>(f1h, W2h, nullptr, slc,
            4096, DM, 2048, FFD, 2048, 2048, (long long)4096 * DM, 1.f, 0);
        reduce2_bias_kernel<<<(4096 * DM / 4 + 255) / 256, blk, 0, stream>>>(
            slc, slc + (long long)4096 * DM, b2, ffoc, 4096 * DM / 4);
    }

    // ---- h2 = LN(h1 + ffo): fp16 only -----------------------------------
    add_ln_kernel<<<T_TOK, blk, 0, stream>>>(h1f, ffo, g2, be2, nullptr, h2h);

    // ---- head: l1 = relu(h2@W3+b3) fp16; LOG = l1@W4p + b4p (N=128) -----
    gemm_nt<1><<<dim3(4, 128, 1), blk, 0, stream>>>(h2h, W3h, b3, l1h,
        T_TOK, 512, DM, DM, 0, 0, 0, 1.f, 1);
    gemm_nt<0><<<dim3(1, 128, 1), blk, 0, stream>>>(l1h, W4h, b4p, LOG,
        T_TOK, 128, 512, 512, 0, 0, 0, 1.f, 0);

    // ---- out = sigmoid(LN75(logits)) ------------------------------------
    ln75_sigmoid_kernel<<<T_TOK, 64, 0, stream>>>(LOG, g3, be3, out);
}

// Round 6
// 1212.027 us; speedup vs baseline: 6.3436x; 1.0342x over previous
//
#include <hip/hip_runtime.h>
#include <hip/hip_fp16.h>
#include <math.h>

// Problem constants
#define DM    1024
#define FFD   4096
#define VOCAB 32000
#define NCAT  75
#define UNK_IDX 1
#define EPS   1e-5f
#define NB    8
#define SEQ   2048
#define T_TOK (NB*SEQ)   // 16384 tokens

using u16   = unsigned short;
using half_t = _Float16;
using half8 = __attribute__((ext_vector_type(8))) _Float16;  // MFMA A/B frag (4 VGPRs)
using f32x4 = __attribute__((ext_vector_type(4))) float;     // MFMA C/D frag

struct alignas(8) h4 { half_t s[4]; };

// async global->LDS, 16 B per lane; LDS dest = wave-uniform base + lane*16
__device__ __forceinline__ void async16(const half_t* g, half_t* l) {
    __builtin_amdgcn_global_load_lds(
        (const __attribute__((address_space(1))) void*)g,
        (__attribute__((address_space(3))) void*)l,
        16, 0, 0);
}

// ---------------------------------------------------------------------------
// Positional-encoding table [SEQ][DM] fp32 (computed once, shared by batch)
// ---------------------------------------------------------------------------
__global__ __launch_bounds__(256)
void pe_kernel(float* __restrict__ pe)
{
    int gid = blockIdx.x * blockDim.x + threadIdx.x;   // over SEQ*DM
    if (gid >= SEQ * DM) return;
    int dcol = gid & (DM - 1);
    int t    = gid >> 10;
    int p = dcol >> 1;
    float power = (float)p / 512.0f;
    float denom = powf(10000.0f, power);
    float ang = (float)t / denom;
    pe[gid] = (dcol & 1) ? cosf(ang) : sinf(ang);
}

// ---------------------------------------------------------------------------
// Embedding gather + PE add -> Xf (fp32) and Xh (fp16), float4-vectorized
// ---------------------------------------------------------------------------
__global__ __launch_bounds__(256)
void embed_pos_kernel(const int* __restrict__ idx,
                      const float* __restrict__ emb,
                      const float* __restrict__ pe,
                      float* __restrict__ xf, half_t* __restrict__ xh)
{
    int gid4 = blockIdx.x * blockDim.x + threadIdx.x;  // over T_TOK*DM/4
    if (gid4 >= T_TOK * DM / 4) return;
    int tok = gid4 >> 8;            // DM/4 = 256 float4 per token
    int c4  = (gid4 & 255) << 2;
    int t   = tok & (SEQ - 1);
    int id = idx[tok];
    if (id >= VOCAB || id < 0) id = UNK_IDX;
    float4 e = *(const float4*)(emb + (long long)id * DM + c4);
    float4 q = *(const float4*)(pe + (long long)t * DM + c4);
    float4 v = make_float4(e.x + q.x, e.y + q.y, e.z + q.z, e.w + q.w);
    *(float4*)(xf + (long long)tok * DM + c4) = v;
    h4 pk = {{(half_t)v.x, (half_t)v.y, (half_t)v.z, (half_t)v.w}};
    *(h4*)(xh + (long long)tok * DM + c4) = pk;
}

// ---------------------------------------------------------------------------
// Weight transpose + fp32->fp16: in [K,N] fp32 -> out [Npad,K] fp16
// ---------------------------------------------------------------------------
__global__ __launch_bounds__(256)
void transpose_h_kernel(const float* __restrict__ in, half_t* __restrict__ out,
                        int K, int N, int Npad)
{
    __shared__ float t[32][33];
    int n0 = blockIdx.x * 32, k0 = blockIdx.y * 32;
    int tx = threadIdx.x & 31, ty = threadIdx.x >> 5;   // ty 0..7
#pragma unroll
    for (int i = 0; i < 4; i++) {
        int k = k0 + ty + i * 8, n = n0 + tx;
        t[ty + i * 8][tx] = (k < K && n < N) ? in[(long long)k * N + n] : 0.f;
    }
    __syncthreads();
#pragma unroll
    for (int i = 0; i < 4; i++) {
        int n = n0 + ty + i * 8, k = k0 + tx;
        if (n < Npad && k < K)
            out[(long long)n * K + k] = (half_t)t[tx][ty + i * 8];
    }
}

// pad b4 [75] -> b4p [128]
__global__ __launch_bounds__(128)
void pad_bias_kernel(const float* __restrict__ b, float* __restrict__ bp)
{
    int i = threadIdx.x;
    bp[i] = (i < NCAT) ? b[i] : 0.f;
}

// ---------------------------------------------------------------------------
// fp16 MFMA NT GEMM, software-pipelined dbuf K-loop (m97 shape).
//   C = scale*(A @ B^T) + bias [+ resid] [,relu]; fp16 in, fp32 acc.
//   128x128 tile, BK=32, 256 thr = 4 waves (2x2), 4x4 16x16x32 MFMA/wave.
//   LDS: 2 tensors x 2 buffers x 8 KB = 32 KB; XOR chunk swizzle on (row&3).
// OUT_MODE: 0 = fp32 [M,N] at C + z*sC (resid supported here);
//           1 = fp16 [M,N]; 2 = fp16 KV-transposed [b][n][t].
// ---------------------------------------------------------------------------
template<int OUT_MODE>
__global__ __launch_bounds__(256)
void gemm_nt(const half_t* __restrict__ A, const half_t* __restrict__ B,
             const float* __restrict__ bias, const float* __restrict__ resid,
             void* __restrict__ Cout,
             int M, int N, int K, int ld,
             long long sA, long long sB, long long sC,
             float scale, int do_relu)
{
    A += (long long)blockIdx.z * sA;
    B += (long long)blockIdx.z * sB;
    const int tid  = threadIdx.x;
    const int lane = tid & 63;
    const int w    = tid >> 6;          // wave 0..3
    const int wm   = w >> 1, wn = w & 1;
    const long long row0 = (long long)blockIdx.y * 128;
    const long long col0 = (long long)blockIdx.x * 128;

    __shared__ half_t smem[4 * 4096];   // 2 tensors x 2 buffers x 8 KB
    half_t* const As = smem;
    half_t* const Bs = smem + 2 * 4096;

    f32x4 acc[4][4];
    const f32x4 zero = {0.f, 0.f, 0.f, 0.f};
#pragma unroll
    for (int i = 0; i < 4; i++)
#pragma unroll
        for (int j = 0; j < 4; j++) acc[i][j] = zero;

    const int ldrow = lane >> 2;                                  // staging row in 16-row chunk
    const int swcol = (((lane & 3) << 3)) ^ ((ldrow & 3) << 3);   // swizzled source col
    const int fr    = lane & 15;                                  // fragment row
    const int kk8   = (lane >> 4) << 3;                           // fragment k offset

    const int KT = K / 32;

#define ISSUE(k0, buf)                                                         \
    {                                                                          \
        _Pragma("unroll")                                                      \
        for (int it = 0; it < 2; ++it) {                                       \
            int rb = (it * 4 + w) * 16;                                        \
            long long ao = (row0 + rb + ldrow) * (long long)ld + (k0) + swcol; \
            long long bo = (col0 + rb + ldrow) * (long long)ld + (k0) + swcol; \
            async16(A + ao, As + (buf) * 4096 + rb * 32);                      \
            async16(B + bo, Bs + (buf) * 4096 + rb * 32);                      \
        }                                                                      \
    }

    ISSUE(0, 0);
    for (int kt = 0; kt < KT; ++kt) {
        const int cur = kt & 1;
        __syncthreads();                 // cur buffer ready; prev consumers done
        if (kt + 1 < KT) ISSUE((kt + 1) * 32, cur ^ 1);

        half8 af[4], bf[4];
#pragma unroll
        for (int i = 0; i < 4; ++i) {
            int r   = wm * 64 + i * 16 + fr;
            int off = cur * 4096 + r * 32 + (kk8 ^ ((r & 3) << 3));
            af[i] = *(const half8*)(As + off);
        }
#pragma unroll
        for (int j = 0; j < 4; ++j) {
            int r   = wn * 64 + j * 16 + fr;
            int off = cur * 4096 + r * 32 + (kk8 ^ ((r & 3) << 3));
            bf[j] = *(const half8*)(Bs + off);
        }
#pragma unroll
        for (int i = 0; i < 4; ++i)
#pragma unroll
            for (int j = 0; j < 4; ++j)
                acc[i][j] = __builtin_amdgcn_mfma_f32_16x16x32_f16(
                    af[i], bf[j], acc[i][j], 0, 0, 0);
    }
#undef ISSUE

    // Epilogue. C/D layout: col = lane&15, row = (lane>>4)*4 + reg
    const int qr = (lane >> 4) * 4;
    const int lc = lane & 15;
    const float* rz = resid ? resid + (long long)blockIdx.z * sC : nullptr;
#pragma unroll
    for (int i = 0; i < 4; ++i) {
#pragma unroll
        for (int j = 0; j < 4; ++j) {
            long long gc = col0 + wn * 64 + j * 16 + lc;
            float bv = bias ? bias[gc] : 0.f;
            if (OUT_MODE == 2) {
                long long gr = row0 + wm * 64 + i * 16 + qr;  // 4 consecutive tokens
                int b  = (int)(gr >> 11);
                int tl = (int)(gr & (SEQ - 1));
                h4 pk;
#pragma unroll
                for (int r = 0; r < 4; ++r) {
                    float f = acc[i][j][r] * scale + bv;
                    if (do_relu) f = fmaxf(f, 0.f);
                    pk.s[r] = (half_t)f;
                }
                half_t* C = (half_t*)Cout;
                *(h4*)(C + (long long)b * N * SEQ + gc * SEQ + tl) = pk;
            } else if (OUT_MODE == 1) {
                half_t* C = (half_t*)Cout + blockIdx.z * sC;
#pragma unroll
                for (int r = 0; r < 4; ++r) {
                    long long gr = row0 + wm * 64 + i * 16 + qr + r;
                    float f = acc[i][j][r] * scale + bv;
                    if (do_relu) f = fmaxf(f, 0.f);
                    C[gr * N + gc] = (half_t)f;
                }
            } else {
                float* C = (float*)Cout + blockIdx.z * sC;
#pragma unroll
                for (int r = 0; r < 4; ++r) {
                    long long gr = row0 + wm * 64 + i * 16 + qr + r;
                    float f = acc[i][j][r] * scale + bv;
                    if (do_relu) f = fmaxf(f, 0.f);
                    if (rz) f += rz[gr * N + gc];
                    C[gr * N + gc] = f;
                }
            }
        }
    }
}

// ---------------------------------------------------------------------------
// LN(X [+ Y]) * g + b over DM=1024, float4-vectorized, one block/row.
// In-place safe (outf may alias X): all reads precede writes.
// ---------------------------------------------------------------------------
__global__ __launch_bounds__(256)
void add_ln_kernel(const float* __restrict__ X, const float* __restrict__ Y,
                   const float* __restrict__ g, const float* __restrict__ b,
                   float* __restrict__ outf, half_t* __restrict__ outh)
{
    int row = blockIdx.x;
    int tid = threadIdx.x;
    float4 v = ((const float4*)(X + (long long)row * DM))[tid];
    if (Y) {
        float4 y = ((const float4*)(Y + (long long)row * DM))[tid];
        v.x += y.x; v.y += y.y; v.z += y.z; v.w += y.w;
    }
    float s  = v.x + v.y + v.z + v.w;
    float s2 = v.x * v.x + v.y * v.y + v.z * v.z + v.w * v.w;
#pragma unroll
    for (int o = 1; o < 64; o <<= 1) {
        s  += __shfl_xor(s,  o, 64);
        s2 += __shfl_xor(s2, o, 64);
    }
    __shared__ float rs[4], rs2[4], stats[2];
    int wid = tid >> 6;
    if ((tid & 63) == 0) { rs[wid] = s; rs2[wid] = s2; }
    __syncthreads();
    if (tid == 0) {
        float S  = rs[0] + rs[1] + rs[2] + rs[3];
        float S2 = rs2[0] + rs2[1] + rs2[2] + rs2[3];
        float mean = S / (float)DM;
        float var  = S2 / (float)DM - mean * mean;   // biased var == jnp.var
        stats[0] = mean;
        stats[1] = rsqrtf(var + EPS);
    }
    __syncthreads();
    float mean = stats[0], rstd = stats[1];
    float4 gg = ((const float4*)g)[tid];
    float4 bb = ((const float4*)b)[tid];
    float4 o;
    o.x = (v.x - mean) * rstd * gg.x + bb.x;
    o.y = (v.y - mean) * rstd * gg.y + bb.y;
    o.z = (v.z - mean) * rstd * gg.z + bb.z;
    o.w = (v.w - mean) * rstd * gg.w + bb.w;
    if (outf) ((float4*)(outf + (long long)row * DM))[tid] = o;
    h4 pk = {{(half_t)o.x, (half_t)o.y, (half_t)o.z, (half_t)o.w}};
    *(h4*)(outh + (long long)row * DM + tid * 4) = pk;
}

// ---------------------------------------------------------------------------
// out[row,:] = sigmoid(LN75(L[row,0:75]) * g + b); L leading dim 128
// ---------------------------------------------------------------------------
__global__ __launch_bounds__(64)
void ln75_sigmoid_kernel(const float* __restrict__ L,
                         const float* __restrict__ g, const float* __restrict__ b,
                         float* __restrict__ out)
{
    int row = blockIdx.x;
    int t   = threadIdx.x;
    const float* lr = L + (long long)row * 128;
    float e0 = (t < NCAT) ? lr[t] : 0.f;
    float e1 = (t + 64 < NCAT) ? lr[t + 64] : 0.f;
    float s  = e0 + e1;
    float s2 = e0 * e0 + e1 * e1;
#pragma unroll
    for (int o = 1; o < 64; o <<= 1) {
        s  += __shfl_xor(s,  o, 64);
        s2 += __shfl_xor(s2, o, 64);
    }
    float mean = s / (float)NCAT;
    float var  = s2 / (float)NCAT - mean * mean;
    float rstd = rsqrtf(var + EPS);
    if (t < NCAT) {
        float z = (e0 - mean) * rstd * g[t] + b[t];
        out[(long long)row * NCAT + t] = 1.f / (1.f + expf(-z));
    }
    if (t + 64 < NCAT) {
        float z = (e1 - mean) * rstd * g[t + 64] + b[t + 64];
        out[(long long)row * NCAT + t + 64] = 1.f / (1.f + expf(-z));
    }
}

// ---------------------------------------------------------------------------
// Orchestration. Attention fully folded:
//   (QK^T/8)V Wu + bu + x == Q @ M2t^T + bu + x,
//   ktv2[b][k][v] = 0.125 * sum_t K[t,k]V[t,v]  = NT(Kt, Vt) * 0.125
//   M2t[b][n][k]  = sum_v Wu[v,n] ktv2[k][v]    = NT(Wuh, ktv2[b])
//   usum          = NT(Q, M2t[b]) + bu + Xf     (fp32, residual fused)
// Regions (~330 MB):
//   R_A 64MB: Xf fp32 -> ffo fp32
//   R_B 32MB: Xh fp16 -> h2h fp16
//   R_C 32MB: Qh fp16 -> h1h fp16
//   R_D 64MB: Kt|Vt fp16 -> f1h fp16 [8192,4096] chunk
//   R_E 64MB: usum fp32 -> h1f fp32 (in-place LN)
//   R_F 32MB: ktv2|M2t fp16 -> l1h fp16
//   R_G  8MB: LOG fp32 [16384,128];  R_PE 8MB: pe table
// ---------------------------------------------------------------------------
extern "C" void kernel_launch(void* const* d_in, const int* in_sizes, int n_in,
                              void* d_out, int out_size, void* d_ws, size_t ws_size,
                              hipStream_t stream)
{
    const int*   idx = (const int*)  d_in[0];
    const float* emb = (const float*)d_in[1];
    const float* Wq  = (const float*)d_in[2];
    const float* bq  = (const float*)d_in[3];
    const float* Wk  = (const float*)d_in[4];
    const float* bk  = (const float*)d_in[5];
    const float* Wv  = (const float*)d_in[6];
    const float* bv  = (const float*)d_in[7];
    const float* Wu  = (const float*)d_in[8];
    const float* bu  = (const float*)d_in[9];
    const float* g1  = (const float*)d_in[10];
    const float* be1 = (const float*)d_in[11];
    const float* W1  = (const float*)d_in[12];
    const float* b1  = (const float*)d_in[13];
    const float* W2  = (const float*)d_in[14];
    const float* b2  = (const float*)d_in[15];
    const float* g2  = (const float*)d_in[16];
    const float* be2 = (const float*)d_in[17];
    const float* W3  = (const float*)d_in[18];
    const float* b3  = (const float*)d_in[19];
    const float* W4  = (const float*)d_in[20];
    const float* b4  = (const float*)d_in[21];
    const float* g3  = (const float*)d_in[22];
    const float* be3 = (const float*)d_in[23];

    const long long TD  = (long long)T_TOK * DM;       // 16.78M
    char* p = (char*)d_ws;
    char* R_A = p; p += TD * 4;
    char* R_B = p; p += TD * 2;
    char* R_C = p; p += TD * 2;
    char* R_D = p; p += TD * 2;                        // 32 MB (Kt) ...
    char* R_D2 = p; p += TD * 2;                       // 32 MB (Vt); R_D..R_D2 = 64MB f1h
    char* R_E = p; p += TD * 4;
    char* R_F = p; p += (long long)NB * DM * DM * 4;   // 32 MB
    char* R_G = p; p += (long long)T_TOK * 128 * 4;    // 8 MB
    float* pe = (float*)p; p += (long long)SEQ * DM * 4; // 8 MB
    half_t* Wqh = (half_t*)p; p += DM*DM*2;
    half_t* Wkh = (half_t*)p; p += DM*DM*2;
    half_t* Wvh = (half_t*)p; p += DM*DM*2;
    half_t* Wuh = (half_t*)p; p += DM*DM*2;
    half_t* W1h = (half_t*)p; p += (long long)FFD*DM*2;
    half_t* W2h = (half_t*)p; p += (long long)DM*FFD*2;
    half_t* W3h = (half_t*)p; p += 512*DM*2;
    half_t* W4h = (half_t*)p; p += 128*512*2;
    float*  b4p = (float*)p;  p += 128*4;

    float*  Xf   = (float*)R_A;
    float*  ffo  = (float*)R_A;
    half_t* Xh   = (half_t*)R_B;
    half_t* h2h  = (half_t*)R_B;
    half_t* Qh   = (half_t*)R_C;
    half_t* h1h  = (half_t*)R_C;
    half_t* Kt   = (half_t*)R_D;            // [8][1024][2048]
    half_t* Vt   = (half_t*)R_D2;
    half_t* f1h  = (half_t*)R_D;            // [8192,4096] chunk (Kt+Vt dead)
    float*  usum = (float*)R_E;             // x + u (fp32) -> h1f in-place
    float*  h1f  = (float*)R_E;
    half_t* ktv2 = (half_t*)R_F;            // [8][1024][1024]
    half_t* M2t  = (half_t*)(R_F + (long long)NB*DM*DM*2);
    half_t* l1h  = (half_t*)R_F;            // [16384,512]
    float*  LOG  = (float*)R_G;
    float*  out  = (float*)d_out;

    dim3 blk(256);

    // ---- weight transpose fp32 [K,N] -> fp16 [Npad,K]; PE table ---------
    transpose_h_kernel<<<dim3(32, 32),  blk, 0, stream>>>(Wq, Wqh, DM, DM, DM);
    transpose_h_kernel<<<dim3(32, 32),  blk, 0, stream>>>(Wk, Wkh, DM, DM, DM);
    transpose_h_kernel<<<dim3(32, 32),  blk, 0, stream>>>(Wv, Wvh, DM, DM, DM);
    transpose_h_kernel<<<dim3(32, 32),  blk, 0, stream>>>(Wu, Wuh, DM, DM, DM);
    transpose_h_kernel<<<dim3(128, 32), blk, 0, stream>>>(W1, W1h, DM, FFD, FFD);
    transpose_h_kernel<<<dim3(32, 128), blk, 0, stream>>>(W2, W2h, FFD, DM, DM);
    transpose_h_kernel<<<dim3(16, 32),  blk, 0, stream>>>(W3, W3h, DM, 512, 512);
    transpose_h_kernel<<<dim3(4, 16),   blk, 0, stream>>>(W4, W4h, 512, NCAT, 128);
    pad_bias_kernel<<<1, 128, 0, stream>>>(b4, b4p);
    pe_kernel<<<(SEQ * DM + 255) / 256, blk, 0, stream>>>(pe);

    // ---- x = emb[idx] + pe  (gather, float4) ----------------------------
    embed_pos_kernel<<<(T_TOK * DM / 4 + 255) / 256, blk, 0, stream>>>(idx, emb, pe, Xf, Xh);

    // ---- QKV: Q normal; K,V transposed [b][dm][seq] ---------------------
    gemm_nt<1><<<dim3(8, 128, 1), blk, 0, stream>>>(Xh, Wqh, bq, nullptr, Qh,
        T_TOK, DM, DM, DM, 0, 0, 0, 1.f, 0);
    gemm_nt<2><<<dim3(8, 128, 1), blk, 0, stream>>>(Xh, Wkh, bk, nullptr, Kt,
        T_TOK, DM, DM, DM, 0, 0, 0, 1.f, 0);
    gemm_nt<2><<<dim3(8, 128, 1), blk, 0, stream>>>(Xh, Wvh, bv, nullptr, Vt,
        T_TOK, DM, DM, DM, 0, 0, 0, 1.f, 0);

    // ---- ktv2[b][k][v] = NT(Kt[b], Vt[b]) * 0.125 -----------------------
    gemm_nt<1><<<dim3(8, 8, NB), blk, 0, stream>>>(Kt, Vt, nullptr, nullptr, ktv2,
        DM, DM, SEQ, SEQ, (long long)DM * SEQ, (long long)DM * SEQ, (long long)DM * DM, 0.125f, 0);

    // ---- M2t[b][n][k] = NT(Wuh, ktv2[b]) --------------------------------
    gemm_nt<1><<<dim3(8, 8, NB), blk, 0, stream>>>(Wuh, ktv2, nullptr, nullptr, M2t,
        DM, DM, DM, DM, 0, (long long)DM * DM, (long long)DM * DM, 1.f, 0);

    // ---- usum = NT(Q, M2t[b]) + bu + Xf  (fp32, residual fused) ---------
    gemm_nt<0><<<dim3(8, 16, NB), blk, 0, stream>>>(Qh, M2t, bu, Xf, usum,
        SEQ, DM, DM, DM, (long long)SEQ * DM, (long long)DM * DM, (long long)SEQ * DM, 1.f, 0);

    // ---- h1 = LN(usum): in-place fp32 + fp16 ----------------------------
    add_ln_kernel<<<T_TOK, blk, 0, stream>>>(usum, nullptr, g1, be1, h1f, h1h);

    // ---- FFN, 2 chunks of 8192 rows; no split-K -------------------------
    for (int c = 0; c < 2; c++) {
        const half_t* h1c  = h1h + (long long)c * 8192 * DM;
        float*        ffoc = ffo + (long long)c * 8192 * DM;
        gemm_nt<1><<<dim3(32, 64, 1), blk, 0, stream>>>(h1c, W1h, b1, nullptr, f1h,
            8192, FFD, DM, DM, 0, 0, 0, 1.f, 1);
        gemm_nt<0><<<dim3(8, 64, 1), blk, 0, stream>>>(f1h, W2h, b2, nullptr, ffoc,
            8192, DM, FFD, FFD, 0, 0, 0, 1.f, 0);
    }

    // ---- h2 = LN(h1 + ffo): fp16 only -----------------------------------
    add_ln_kernel<<<T_TOK, blk, 0, stream>>>(h1f, ffo, g2, be2, nullptr, h2h);

    // ---- head: l1 = relu(h2@W3+b3) fp16; LOG = l1@W4p + b4p (N=128) -----
    gemm_nt<1><<<dim3(4, 128, 1), blk, 0, stream>>>(h2h, W3h, b3, nullptr, l1h,
        T_TOK, 512, DM, DM, 0, 0, 0, 1.f, 1);
    gemm_nt<0><<<dim3(1, 128, 1), blk, 0, stream>>>(l1h, W4h, b4p, nullptr, LOG,
        T_TOK, 128, 512, 512, 0, 0, 0, 1.f, 0);

    // ---- out = sigmoid(LN75(logits)) ------------------------------------
    ln75_sigmoid_kernel<<<T_TOK, 64, 0, stream>>>(LOG, g3, be3, out);
}

// Round 8
// 1113.008 us; speedup vs baseline: 6.9080x; 1.0890x over previous
//
#include <hip/hip_runtime.h>
#include <hip/hip_fp16.h>
#include <math.h>

// Problem constants
#define DM    1024
#define FFD   4096
#define VOCAB 32000
#define NCAT  75
#define UNK_IDX 1
#define EPS   1e-5f
#define NB    8
#define SEQ   2048
#define T_TOK (NB*SEQ)   // 16384 tokens

using u16   = unsigned short;
using half_t = _Float16;
using half8 = __attribute__((ext_vector_type(8))) _Float16;  // MFMA A/B frag (4 VGPRs)
using f32x4 = __attribute__((ext_vector_type(4))) float;     // MFMA C/D frag

struct alignas(8) h4 { half_t s[4]; };

// async global->LDS, 16 B per lane; LDS dest = wave-uniform base + lane*16
__device__ __forceinline__ void async16(const half_t* g, half_t* l) {
    __builtin_amdgcn_global_load_lds(
        (const __attribute__((address_space(1))) void*)g,
        (__attribute__((address_space(3))) void*)l,
        16, 0, 0);
}

// ---------------------------------------------------------------------------
// Positional-encoding table [SEQ][DM] fp32 (computed once, shared by batch)
// ---------------------------------------------------------------------------
__global__ __launch_bounds__(256)
void pe_kernel(float* __restrict__ pe)
{
    int gid = blockIdx.x * blockDim.x + threadIdx.x;   // over SEQ*DM
    if (gid >= SEQ * DM) return;
    int dcol = gid & (DM - 1);
    int t    = gid >> 10;
    int p = dcol >> 1;
    float power = (float)p / 512.0f;
    float denom = powf(10000.0f, power);
    float ang = (float)t / denom;
    pe[gid] = (dcol & 1) ? cosf(ang) : sinf(ang);
}

// ---------------------------------------------------------------------------
// Embedding gather + PE add -> Xf (fp32) and Xh (fp16), float4-vectorized
// ---------------------------------------------------------------------------
__global__ __launch_bounds__(256)
void embed_pos_kernel(const int* __restrict__ idx,
                      const float* __restrict__ emb,
                      const float* __restrict__ pe,
                      float* __restrict__ xf, half_t* __restrict__ xh)
{
    int gid4 = blockIdx.x * blockDim.x + threadIdx.x;  // over T_TOK*DM/4
    if (gid4 >= T_TOK * DM / 4) return;
    int tok = gid4 >> 8;            // DM/4 = 256 float4 per token
    int c4  = (gid4 & 255) << 2;
    int t   = tok & (SEQ - 1);
    int id = idx[tok];
    if (id >= VOCAB || id < 0) id = UNK_IDX;
    float4 e = *(const float4*)(emb + (long long)id * DM + c4);
    float4 q = *(const float4*)(pe + (long long)t * DM + c4);
    float4 v = make_float4(e.x + q.x, e.y + q.y, e.z + q.z, e.w + q.w);
    *(float4*)(xf + (long long)tok * DM + c4) = v;
    h4 pk = {{(half_t)v.x, (half_t)v.y, (half_t)v.z, (half_t)v.w}};
    *(h4*)(xh + (long long)tok * DM + c4) = pk;
}

// ---------------------------------------------------------------------------
// Weight transpose + fp32->fp16: in [K,N] fp32 -> out [Npad,K] fp16
// ---------------------------------------------------------------------------
__global__ __launch_bounds__(256)
void transpose_h_kernel(const float* __restrict__ in, half_t* __restrict__ out,
                        int K, int N, int Npad)
{
    __shared__ float t[32][33];
    int n0 = blockIdx.x * 32, k0 = blockIdx.y * 32;
    int tx = threadIdx.x & 31, ty = threadIdx.x >> 5;   // ty 0..7
#pragma unroll
    for (int i = 0; i < 4; i++) {
        int k = k0 + ty + i * 8, n = n0 + tx;
        t[ty + i * 8][tx] = (k < K && n < N) ? in[(long long)k * N + n] : 0.f;
    }
    __syncthreads();
#pragma unroll
    for (int i = 0; i < 4; i++) {
        int n = n0 + ty + i * 8, k = k0 + tx;
        if (n < Npad && k < K)
            out[(long long)n * K + k] = (half_t)t[tx][ty + i * 8];
    }
}

// pad b4 [75] -> b4p [128]
__global__ __launch_bounds__(128)
void pad_bias_kernel(const float* __restrict__ b, float* __restrict__ bp)
{
    int i = threadIdx.x;
    bp[i] = (i < NCAT) ? b[i] : 0.f;
}

// ---------------------------------------------------------------------------
// fp16 MFMA NT GEMM, software-pipelined dbuf K-loop (m97 shape) + LDS-staged
// coalesced epilogue.
//   C = scale*(A @ B^T) + bias [+ resid] [,relu]; fp16 in, fp32 acc.
//   128x128 tile, BK=32, 256 thr = 4 waves (2x2), 4x4 16x16x32 MFMA/wave.
//   K-loop LDS: 2 tensors x 2 buffers x 8 KB = 32 KB (XOR chunk swizzle).
//   Epilogue: same 32 KB re-staged as fp32 [32][132] chunks -> float4 stores.
// OUT_MODE: 0 = fp32 [M,N] at C + z*sC (+resid); 1 = fp16 [M,N];
//           2 = fp16 KV-transposed [b][n][t], b=row>>11, t=row&2047.
// ---------------------------------------------------------------------------
template<int OUT_MODE>
__global__ __launch_bounds__(256)
void gemm_nt(const half_t* __restrict__ A, const half_t* __restrict__ B,
             const float* __restrict__ bias, const float* __restrict__ resid,
             void* __restrict__ Cout,
             int M, int N, int K, int ld,
             long long sA, long long sB, long long sC,
             float scale, int do_relu)
{
    A += (long long)blockIdx.z * sA;
    B += (long long)blockIdx.z * sB;
    const int tid  = threadIdx.x;
    const int lane = tid & 63;
    const int w    = tid >> 6;          // wave 0..3
    const int wm   = w >> 1, wn = w & 1;
    const long long row0 = (long long)blockIdx.y * 128;
    const long long col0 = (long long)blockIdx.x * 128;

    __shared__ half_t smem[4 * 4096];   // 2 tensors x 2 buffers x 8 KB
    half_t* const As = smem;
    half_t* const Bs = smem + 2 * 4096;

    f32x4 acc[4][4];
    const f32x4 zero = {0.f, 0.f, 0.f, 0.f};
#pragma unroll
    for (int i = 0; i < 4; i++)
#pragma unroll
        for (int j = 0; j < 4; j++) acc[i][j] = zero;

    const int ldrow = lane >> 2;                                  // staging row in 16-row chunk
    const int swcol = (((lane & 3) << 3)) ^ ((ldrow & 3) << 3);   // swizzled source col
    const int fr    = lane & 15;                                  // fragment row
    const int kk8   = (lane >> 4) << 3;                           // fragment k offset

    const int KT = K / 32;

#define ISSUE(k0, buf)                                                         \
    {                                                                          \
        _Pragma("unroll")                                                      \
        for (int it = 0; it < 2; ++it) {                                       \
            int rb = (it * 4 + w) * 16;                                        \
            long long ao = (row0 + rb + ldrow) * (long long)ld + (k0) + swcol; \
            long long bo = (col0 + rb + ldrow) * (long long)ld + (k0) + swcol; \
            async16(A + ao, As + (buf) * 4096 + rb * 32);                      \
            async16(B + bo, Bs + (buf) * 4096 + rb * 32);                      \
        }                                                                      \
    }

    ISSUE(0, 0);
    for (int kt = 0; kt < KT; ++kt) {
        const int cur = kt & 1;
        __syncthreads();                 // cur buffer ready; prev consumers done
        if (kt + 1 < KT) ISSUE((kt + 1) * 32, cur ^ 1);

        half8 af[4], bf[4];
#pragma unroll
        for (int i = 0; i < 4; ++i) {
            int r   = wm * 64 + i * 16 + fr;
            int off = cur * 4096 + r * 32 + (kk8 ^ ((r & 3) << 3));
            af[i] = *(const half8*)(As + off);
        }
#pragma unroll
        for (int j = 0; j < 4; ++j) {
            int r   = wn * 64 + j * 16 + fr;
            int off = cur * 4096 + r * 32 + (kk8 ^ ((r & 3) << 3));
            bf[j] = *(const half8*)(Bs + off);
        }
#pragma unroll
        for (int i = 0; i < 4; ++i)
#pragma unroll
            for (int j = 0; j < 4; ++j)
                acc[i][j] = __builtin_amdgcn_mfma_f32_16x16x32_f16(
                    af[i], bf[j], acc[i][j], 0, 0, 0);
    }
#undef ISSUE

    // ---- LDS-staged epilogue ------------------------------------------------
    // C/D layout: col = lane&15, row = (lane>>4)*4 + reg. Stage 4 chunks of
    // 32 rows (wm=0: i*16+0..15, wm=1: 64+i*16+0..15) x 128 cols into fp32
    // LDS [32][132], then emit float4-coalesced global traffic.
    float* ls = (float*)smem;           // 32*132*4 = 16.9 KB <= 32 KB
    const int ldp = 132;
    const int qr = (lane >> 4) * 4;
    const int lc = lane & 15;
    float bvj[4];
#pragma unroll
    for (int j = 0; j < 4; ++j)
        bvj[j] = bias ? bias[col0 + wn * 64 + j * 16 + lc] : 0.f;
    const float* rz = (OUT_MODE == 0 && resid) ? resid + (long long)blockIdx.z * sC : nullptr;

#pragma unroll
    for (int i = 0; i < 4; ++i) {
        __syncthreads();                // LDS free (K-loop or previous chunk done)
#pragma unroll
        for (int j = 0; j < 4; ++j) {
            int col = wn * 64 + j * 16 + lc;
#pragma unroll
            for (int r = 0; r < 4; ++r) {
                float f = acc[i][j][r] * scale + bvj[j];
                if (do_relu) f = fmaxf(f, 0.f);
                ls[(wm * 16 + qr + r) * ldp + col] = f;
            }
        }
        __syncthreads();
        if (OUT_MODE == 2) {
            // write along t: idx -> n = idx>>3 (0..127), k = idx&7; rows lr=4k..4k+3
#pragma unroll
            for (int rep = 0; rep < 4; ++rep) {
                int idx = rep * 256 + tid;      // 0..1023
                int n   = idx >> 3;
                int k   = idx & 7;
                int lr0 = k * 4;
                h4 pk;
                long long arow0 = (lr0 < 16 ? 0 : 48) + i * 16 + lr0;
#pragma unroll
                for (int r = 0; r < 4; ++r)
                    pk.s[r] = (half_t)ls[(lr0 + r) * ldp + n];
                long long gr = row0 + arow0;    // 4 consecutive tokens
                int b  = (int)(gr >> 11);
                int tl = (int)(gr & (SEQ - 1));
                half_t* C = (half_t*)Cout;
                *(h4*)(C + (long long)b * N * SEQ + (col0 + n) * SEQ + tl) = pk;
            }
        } else {
#pragma unroll
            for (int rep = 0; rep < 4; ++rep) {
                int idx = rep * 256 + tid;      // 0..1023
                int lr  = idx >> 5;             // 0..31
                int c4  = (idx & 31) << 2;      // col offset 0..124
                long long arow = (lr < 16 ? 0 : 48) + i * 16 + lr;
                float4 v = *(float4*)&ls[lr * ldp + c4];
                long long base = (row0 + arow) * N + col0 + c4;
                if (OUT_MODE == 0) {
                    float* C = (float*)Cout + blockIdx.z * sC;
                    if (rz) {
                        float4 x = *(const float4*)(rz + base);
                        v.x += x.x; v.y += x.y; v.z += x.z; v.w += x.w;
                    }
                    *(float4*)(C + base) = v;
                } else {
                    half_t* C = (half_t*)Cout + blockIdx.z * sC;
                    h4 pk = {{(half_t)v.x, (half_t)v.y, (half_t)v.z, (half_t)v.w}};
                    *(h4*)(C + base) = pk;
                }
            }
        }
    }
}

// ---------------------------------------------------------------------------
// LN(X [+ Y]) * g + b over DM=1024, float4-vectorized, one block/row.
// In-place safe (outf may alias X): all reads precede writes.
// ---------------------------------------------------------------------------
__global__ __launch_bounds__(256)
void add_ln_kernel(const float* __restrict__ X, const float* __restrict__ Y,
                   const float* __restrict__ g, const float* __restrict__ b,
                   float* __restrict__ outf, half_t* __restrict__ outh)
{
    int row = blockIdx.x;
    int tid = threadIdx.x;
    float4 v = ((const float4*)(X + (long long)row * DM))[tid];
    if (Y) {
        float4 y = ((const float4*)(Y + (long long)row * DM))[tid];
        v.x += y.x; v.y += y.y; v.z += y.z; v.w += y.w;
    }
    float s  = v.x + v.y + v.z + v.w;
    float s2 = v.x * v.x + v.y * v.y + v.z * v.z + v.w * v.w;
#pragma unroll
    for (int o = 1; o < 64; o <<= 1) {
        s  += __shfl_xor(s,  o, 64);
        s2 += __shfl_xor(s2, o, 64);
    }
    __shared__ float rs[4], rs2[4], stats[2];
    int wid = tid >> 6;
    if ((tid & 63) == 0) { rs[wid] = s; rs2[wid] = s2; }
    __syncthreads();
    if (tid == 0) {
        float S  = rs[0] + rs[1] + rs[2] + rs[3];
        float S2 = rs2[0] + rs2[1] + rs2[2] + rs2[3];
        float mean = S / (float)DM;
        float var  = S2 / (float)DM - mean * mean;   // biased var == jnp.var
        stats[0] = mean;
        stats[1] = rsqrtf(var + EPS);
    }
    __syncthreads();
    float mean = stats[0], rstd = stats[1];
    float4 gg = ((const float4*)g)[tid];
    float4 bb = ((const float4*)b)[tid];
    float4 o;
    o.x = (v.x - mean) * rstd * gg.x + bb.x;
    o.y = (v.y - mean) * rstd * gg.y + bb.y;
    o.z = (v.z - mean) * rstd * gg.z + bb.z;
    o.w = (v.w - mean) * rstd * gg.w + bb.w;
    if (outf) ((float4*)(outf + (long long)row * DM))[tid] = o;
    h4 pk = {{(half_t)o.x, (half_t)o.y, (half_t)o.z, (half_t)o.w}};
    *(h4*)(outh + (long long)row * DM + tid * 4) = pk;
}

// ---------------------------------------------------------------------------
// out[row,:] = sigmoid(LN75(L[row,0:75]) * g + b); L leading dim 128
// ---------------------------------------------------------------------------
__global__ __launch_bounds__(64)
void ln75_sigmoid_kernel(const float* __restrict__ L,
                         const float* __restrict__ g, const float* __restrict__ b,
                         float* __restrict__ out)
{
    int row = blockIdx.x;
    int t   = threadIdx.x;
    const float* lr = L + (long long)row * 128;
    float e0 = (t < NCAT) ? lr[t] : 0.f;
    float e1 = (t + 64 < NCAT) ? lr[t + 64] : 0.f;
    float s  = e0 + e1;
    float s2 = e0 * e0 + e1 * e1;
#pragma unroll
    for (int o = 1; o < 64; o <<= 1) {
        s  += __shfl_xor(s,  o, 64);
        s2 += __shfl_xor(s2, o, 64);
    }
    float mean = s / (float)NCAT;
    float var  = s2 / (float)NCAT - mean * mean;
    float rstd = rsqrtf(var + EPS);
    if (t < NCAT) {
        float z = (e0 - mean) * rstd * g[t] + b[t];
        out[(long long)row * NCAT + t] = 1.f / (1.f + expf(-z));
    }
    if (t + 64 < NCAT) {
        float z = (e1 - mean) * rstd * g[t + 64] + b[t + 64];
        out[(long long)row * NCAT + t + 64] = 1.f / (1.f + expf(-z));
    }
}

// ---------------------------------------------------------------------------
// Orchestration. Attention fully folded:
//   (QK^T/8)V Wu + bu + x == Q @ M2t^T + bu + x,
//   ktv2[b][k][v] = 0.125 * sum_t K[t,k]V[t,v]  = NT(Kt, Vt) * 0.125
//   M2t[b][n][k]  = sum_v Wu[v,n] ktv2[k][v]    = NT(Wuh, ktv2[b])
//   usum          = NT(Q, M2t[b]) + bu + Xf     (fp32, residual fused)
// ---------------------------------------------------------------------------
extern "C" void kernel_launch(void* const* d_in, const int* in_sizes, int n_in,
                              void* d_out, int out_size, void* d_ws, size_t ws_size,
                              hipStream_t stream)
{
    const int*   idx = (const int*)  d_in[0];
    const float* emb = (const float*)d_in[1];
    const float* Wq  = (const float*)d_in[2];
    const float* bq  = (const float*)d_in[3];
    const float* Wk  = (const float*)d_in[4];
    const float* bk  = (const float*)d_in[5];
    const float* Wv  = (const float*)d_in[6];
    const float* bv  = (const float*)d_in[7];
    const float* Wu  = (const float*)d_in[8];
    const float* bu  = (const float*)d_in[9];
    const float* g1  = (const float*)d_in[10];
    const float* be1 = (const float*)d_in[11];
    const float* W1  = (const float*)d_in[12];
    const float* b1  = (const float*)d_in[13];
    const float* W2  = (const float*)d_in[14];
    const float* b2  = (const float*)d_in[15];
    const float* g2  = (const float*)d_in[16];
    const float* be2 = (const float*)d_in[17];
    const float* W3  = (const float*)d_in[18];
    const float* b3  = (const float*)d_in[19];
    const float* W4  = (const float*)d_in[20];
    const float* b4  = (const float*)d_in[21];
    const float* g3  = (const float*)d_in[22];
    const float* be3 = (const float*)d_in[23];

    const long long TD  = (long long)T_TOK * DM;       // 16.78M
    char* p = (char*)d_ws;
    char* R_A = p; p += TD * 4;
    char* R_B = p; p += TD * 2;
    char* R_C = p; p += TD * 2;
    char* R_D = p; p += TD * 2;                        // 32 MB (Kt) ...
    char* R_D2 = p; p += TD * 2;                       // 32 MB (Vt); R_D..R_D2 = 64MB f1h
    char* R_E = p; p += TD * 4;
    char* R_F = p; p += (long long)NB * DM * DM * 4;   // 32 MB
    char* R_G = p; p += (long long)T_TOK * 128 * 4;    // 8 MB
    float* pe = (float*)p; p += (long long)SEQ * DM * 4; // 8 MB
    half_t* Wqh = (half_t*)p; p += DM*DM*2;
    half_t* Wkh = (half_t*)p; p += DM*DM*2;
    half_t* Wvh = (half_t*)p; p += DM*DM*2;
    half_t* Wuh = (half_t*)p; p += DM*DM*2;
    half_t* W1h = (half_t*)p; p += (long long)FFD*DM*2;
    half_t* W2h = (half_t*)p; p += (long long)DM*FFD*2;
    half_t* W3h = (half_t*)p; p += 512*DM*2;
    half_t* W4h = (half_t*)p; p += 128*512*2;
    float*  b4p = (float*)p;  p += 128*4;

    float*  Xf   = (float*)R_A;
    float*  ffo  = (float*)R_A;
    half_t* Xh   = (half_t*)R_B;
    half_t* h2h  = (half_t*)R_B;
    half_t* Qh   = (half_t*)R_C;
    half_t* h1h  = (half_t*)R_C;
    half_t* Kt   = (half_t*)R_D;            // [8][1024][2048]
    half_t* Vt   = (half_t*)R_D2;
    half_t* f1h  = (half_t*)R_D;            // [8192,4096] chunk (Kt+Vt dead)
    float*  usum = (float*)R_E;             // x + u (fp32) -> h1f in-place
    float*  h1f  = (float*)R_E;
    half_t* ktv2 = (half_t*)R_F;            // [8][1024][1024]
    half_t* M2t  = (half_t*)(R_F + (long long)NB*DM*DM*2);
    half_t* l1h  = (half_t*)R_F;            // [16384,512]
    float*  LOG  = (float*)R_G;
    float*  out  = (float*)d_out;

    dim3 blk(256);

    // ---- weight transpose fp32 [K,N] -> fp16 [Npad,K]; PE table ---------
    transpose_h_kernel<<<dim3(32, 32),  blk, 0, stream>>>(Wq, Wqh, DM, DM, DM);
    transpose_h_kernel<<<dim3(32, 32),  blk, 0, stream>>>(Wk, Wkh, DM, DM, DM);
    transpose_h_kernel<<<dim3(32, 32),  blk, 0, stream>>>(Wv, Wvh, DM, DM, DM);
    transpose_h_kernel<<<dim3(32, 32),  blk, 0, stream>>>(Wu, Wuh, DM, DM, DM);
    transpose_h_kernel<<<dim3(128, 32), blk, 0, stream>>>(W1, W1h, DM, FFD, FFD);
    transpose_h_kernel<<<dim3(32, 128), blk, 0, stream>>>(W2, W2h, FFD, DM, DM);
    transpose_h_kernel<<<dim3(16, 32),  blk, 0, stream>>>(W3, W3h, DM, 512, 512);
    transpose_h_kernel<<<dim3(4, 16),   blk, 0, stream>>>(W4, W4h, 512, NCAT, 128);
    pad_bias_kernel<<<1, 128, 0, stream>>>(b4, b4p);
    pe_kernel<<<(SEQ * DM + 255) / 256, blk, 0, stream>>>(pe);

    // ---- x = emb[idx] + pe  (gather, float4) ----------------------------
    embed_pos_kernel<<<(T_TOK * DM / 4 + 255) / 256, blk, 0, stream>>>(idx, emb, pe, Xf, Xh);

    // ---- QKV: Q normal; K,V transposed [b][dm][seq] ---------------------
    gemm_nt<1><<<dim3(8, 128, 1), blk, 0, stream>>>(Xh, Wqh, bq, nullptr, Qh,
        T_TOK, DM, DM, DM, 0, 0, 0, 1.f, 0);
    gemm_nt<2><<<dim3(8, 128, 1), blk, 0, stream>>>(Xh, Wkh, bk, nullptr, Kt,
        T_TOK, DM, DM, DM, 0, 0, 0, 1.f, 0);
    gemm_nt<2><<<dim3(8, 128, 1), blk, 0, stream>>>(Xh, Wvh, bv, nullptr, Vt,
        T_TOK, DM, DM, DM, 0, 0, 0, 1.f, 0);

    // ---- ktv2[b][k][v] = NT(Kt[b], Vt[b]) * 0.125 -----------------------
    gemm_nt<1><<<dim3(8, 8, NB), blk, 0, stream>>>(Kt, Vt, nullptr, nullptr, ktv2,
        DM, DM, SEQ, SEQ, (long long)DM * SEQ, (long long)DM * SEQ, (long long)DM * DM, 0.125f, 0);

    // ---- M2t[b][n][k] = NT(Wuh, ktv2[b]) --------------------------------
    gemm_nt<1><<<dim3(8, 8, NB), blk, 0, stream>>>(Wuh, ktv2, nullptr, nullptr, M2t,
        DM, DM, DM, DM, 0, (long long)DM * DM, (long long)DM * DM, 1.f, 0);

    // ---- usum = NT(Q, M2t[b]) + bu + Xf  (fp32, residual fused) ---------
    gemm_nt<0><<<dim3(8, 16, NB), blk, 0, stream>>>(Qh, M2t, bu, Xf, usum,
        SEQ, DM, DM, DM, (long long)SEQ * DM, (long long)DM * DM, (long long)SEQ * DM, 1.f, 0);

    // ---- h1 = LN(usum): in-place fp32 + fp16 ----------------------------
    add_ln_kernel<<<T_TOK, blk, 0, stream>>>(usum, nullptr, g1, be1, h1f, h1h);

    // ---- FFN, 2 chunks of 8192 rows; no split-K -------------------------
    for (int c = 0; c < 2; c++) {
        const half_t* h1c  = h1h + (long long)c * 8192 * DM;
        float*        ffoc = ffo + (long long)c * 8192 * DM;
        gemm_nt<1><<<dim3(32, 64, 1), blk, 0, stream>>>(h1c, W1h, b1, nullptr, f1h,
            8192, FFD, DM, DM, 0, 0, 0, 1.f, 1);
        gemm_nt<0><<<dim3(8, 64, 1), blk, 0, stream>>>(f1h, W2h, b2, nullptr, ffoc,
            8192, DM, FFD, FFD, 0, 0, 0, 1.f, 0);
    }

    // ---- h2 = LN(h1 + ffo): fp16 only -----------------------------------
    add_ln_kernel<<<T_TOK, blk, 0, stream>>>(h1f, ffo, g2, be2, nullptr, h2h);

    // ---- head: l1 = relu(h2@W3+b3) fp16; LOG = l1@W4p + b4p (N=128) -----
    gemm_nt<1><<<dim3(4, 128, 1), blk, 0, stream>>>(h2h, W3h, b3, nullptr, l1h,
        T_TOK, 512, DM, DM, 0, 0, 0, 1.f, 1);
    gemm_nt<0><<<dim3(1, 128, 1), blk, 0, stream>>>(l1h, W4h, b4p, nullptr, LOG,
        T_TOK, 128, 512, 512, 0, 0, 0, 1.f, 0);

    // ---- out = sigmoid(LN75(logits)) ------------------------------------
    ln75_sigmoid_kernel<<<T_TOK, 64, 0, stream>>>(LOG, g3, be3, out);
}